// Round 1
// 1457.173 us; speedup vs baseline: 1.2212x; 1.2212x over previous
//
#include <hip/hip_runtime.h>
#include <hip/hip_bf16.h>
#include <cstdio>

// GCNTox21 — round 12. r11 counters: conv1 425us with VALUBusy 28%, HBM 7.8%,
// occupancy 21%, 0 bank conflicts -> latency-bound, not pipe-bound.
// Changes vs r11:
//  (1) conv_k no longer does the Wb matvec epilogue (was ~128 shfl + 128 LDS
//      reads + a 128-deep serial FMA chain per node). It writes the mean-
//      aggregated message m IN PLACE into Pd (safe: Pd[v] read only by node
//      v's own wave, before the write; Ps is a separate buffer). A new
//      streaming matvec_k<H,Fo> computes y = m@Wb+bb with the deg>0 mask.
//  (2) edge loop unrolled 4x: 4 independent srcs->Ps gather chains + 8
//      independent uint4 e16 loads in flight per iteration (was 2).
//  (3) SL==64 (conv1, conv2): v scalarized via readfirstlane so row_ptr /
//      srcs / e16 addressing is provably wave-uniform (SGPR/scalar loads).
// Keep plain __launch_bounds__(256) — r10 showed (256,4) causes spills.

#define N_NODES 100000
#define N_EDGES 1600000
#define NUM_GRAPHS 4096

typedef unsigned short u16;
typedef unsigned int u32;
typedef _Float16 h2 __attribute__((ext_vector_type(2)));

#if defined(__has_builtin)
#if __has_builtin(__builtin_amdgcn_fdot2)
#define DOT2(a, b, c) __builtin_amdgcn_fdot2((a), (b), (c), false)
#endif
#endif
#ifndef DOT2
#define DOT2(a, b, c) ((c) + (float)(a).x * (float)(b).x + (float)(a).y * (float)(b).y)
#endif

__device__ __forceinline__ float b2f(u16 u) { union { u32 i; float f; } c; c.i = ((u32)u) << 16; return c.f; }
__device__ __forceinline__ float b2f_lo(u32 u) { union { u32 i; float f; } c; c.i = u << 16; return c.f; }
__device__ __forceinline__ float b2f_hi(u32 u) { union { u32 i; float f; } c; c.i = u & 0xffff0000u; return c.f; }
__device__ __forceinline__ u16 f2b(float f) {
    __hip_bfloat16 h = __float2bfloat16(f);
    return *reinterpret_cast<u16*>(&h);
}

template <int CPL>
__device__ __forceinline__ void ld_bf16(const u16* base, float out[CPL]) {
    if constexpr (CPL == 1) {
        out[0] = b2f(*base);
    } else {
        u32 v = *(const u32*)base;
        out[0] = b2f_lo(v); out[1] = b2f_hi(v);
    }
}
template <int CPL>
__device__ __forceinline__ void ld_f32(const float* base, float out[CPL]) {
    if constexpr (CPL == 1) {
        out[0] = *base;
    } else {
        float2 v = *(const float2*)base;
        out[0] = v.x; out[1] = v.y;
    }
}

// ---------------- CSR build ----------------
__global__ __launch_bounds__(256) void hist_k(const int* __restrict__ dst, int* __restrict__ hist) {
    int e = blockIdx.x * 256 + threadIdx.x;
    if (e < N_EDGES) atomicAdd(&hist[dst[e]], 1);
}

__global__ __launch_bounds__(256) void scan_part_k(const int* __restrict__ hist,
        int* __restrict__ excl, int* __restrict__ bsum) {
    __shared__ int sm[256];
    int t = threadIdx.x, b = blockIdx.x;
    int base = b * 1024 + t * 4;
    int v0 = (base + 0 < N_NODES) ? hist[base + 0] : 0;
    int v1 = (base + 1 < N_NODES) ? hist[base + 1] : 0;
    int v2 = (base + 2 < N_NODES) ? hist[base + 2] : 0;
    int v3 = (base + 3 < N_NODES) ? hist[base + 3] : 0;
    int tsum = v0 + v1 + v2 + v3;
    sm[t] = tsum;
    __syncthreads();
    for (int o = 1; o < 256; o <<= 1) {
        int x = (t >= o) ? sm[t - o] : 0;
        __syncthreads();
        sm[t] += x;
        __syncthreads();
    }
    int texcl = sm[t] - tsum;
    if (base + 0 < N_NODES) excl[base + 0] = texcl;
    if (base + 1 < N_NODES) excl[base + 1] = texcl + v0;
    if (base + 2 < N_NODES) excl[base + 2] = texcl + v0 + v1;
    if (base + 3 < N_NODES) excl[base + 3] = texcl + v0 + v1 + v2;
    if (t == 255) bsum[b] = sm[255];
}

__global__ __launch_bounds__(256) void scan_top_k(int* __restrict__ bsum, int* __restrict__ boff,
        int nb, int* __restrict__ row_ptr_last) {
    __shared__ int sm[256];
    int t = threadIdx.x;
    int v = (t < nb) ? bsum[t] : 0;
    sm[t] = v;
    __syncthreads();
    for (int o = 1; o < 256; o <<= 1) {
        int x = (t >= o) ? sm[t - o] : 0;
        __syncthreads();
        sm[t] += x;
        __syncthreads();
    }
    if (t < nb) boff[t] = sm[t] - v;
    if (t == 0) *row_ptr_last = sm[255];
}

__global__ __launch_bounds__(256) void scan_add_k(int* __restrict__ excl, const int* __restrict__ boff,
        int* __restrict__ row_ptr, int* __restrict__ cursor) {
    int i = blockIdx.x * 256 + threadIdx.x;
    if (i >= N_NODES) return;
    int s = excl[i] + boff[i >> 10];
    row_ptr[i] = s;
    cursor[i] = s;
}

__global__ __launch_bounds__(256) void scatter_k(const int* __restrict__ src, const int* __restrict__ dst,
        int* __restrict__ cursor, int* __restrict__ sorted_eid, int* __restrict__ srcs) {
    int e = blockIdx.x * 256 + threadIdx.x;
    if (e < N_EDGES) {
        int p = atomicAdd(&cursor[dst[e]], 1);
        sorted_eid[p] = e;
        srcs[p] = src[e];
    }
}

// ---------------- embeddings ----------------
__global__ __launch_bounds__(256) void edge_emb_k(const float* __restrict__ ea,
        const float* __restrict__ We, const float* __restrict__ be,
        const int* __restrict__ sorted_eid, _Float16* __restrict__ e16s) {
    int idx = blockIdx.x * 256 + threadIdx.x;
    if (idx >= N_EDGES * 16) return;
    int p = idx >> 4, k = idx & 15;
    int e = sorted_eid[p];
    float acc = be[k];
#pragma unroll
    for (int j = 0; j < 8; ++j) acc += ea[(size_t)e * 8 + j] * We[j * 16 + k];
    e16s[idx] = (_Float16)fmaxf(acc, 0.f);
}

__global__ __launch_bounds__(256) void node_emb_k(const float* __restrict__ x,
        const float* __restrict__ Wn, const float* __restrict__ bn_, float* __restrict__ h) {
    int idx = blockIdx.x * 256 + threadIdx.x;
    if (idx >= N_NODES * 64) return;
    int v = idx >> 6, c = idx & 63;
    float acc = bn_[c];
    for (int k = 0; k < 32; ++k) acc += x[(size_t)v * 32 + k] * Wn[(size_t)k * 64 + c];
    h[idx] = fmaxf(acc, 0.f);
}

// ---------------- projections: Pd fp32, Ps bf16 ----------------
template <int F, int H>
__global__ __launch_bounds__(256) void proj_k(const float* __restrict__ h,
        const float* __restrict__ Wa, const float* __restrict__ ba,
        float* __restrict__ Pd, u16* __restrict__ Ps) {
    int idx = blockIdx.x * 256 + threadIdx.x;
    if (idx >= N_NODES * H) return;
    int v = idx / H, c = idx % H;
    float ad = ba[c], as = 0.f;
    const float* hr = h + (size_t)v * F;
    for (int k = 0; k < F; ++k) {
        float hk = hr[k];
        ad += hk * Wa[(size_t)k * H + c];
        as += hk * Wa[(size_t)(F + k) * H + c];
    }
    Pd[idx] = ad;
    Ps[idx] = f2b(as);
}

// ---------------- fused conv: CSR gather + mean; writes m into Pd in place --
template <int H>
__global__ __launch_bounds__(256) void conv_k(
        const int* __restrict__ row_ptr, const int* __restrict__ srcs,
        const _Float16* __restrict__ e16s,
        float* __restrict__ Pd, const u16* __restrict__ Ps,
        const float* __restrict__ Wae) {
    constexpr int SL = (H >= 64) ? 64 : 32;   // lanes per node
    constexpr int NPW = 64 / SL;              // nodes per wave
    constexpr int CPL = H / SL;               // channels per lane
    constexpr int NPB = 4 * NPW;              // nodes per block per iter
    const int wave = threadIdx.x >> 6, lane = threadIdx.x & 63;
    const int sub = lane / SL;
    const int sl = lane % SL;
    const int c0 = sl * CPL;
    h2 w2h[8][CPL];
#pragma unroll
    for (int k2 = 0; k2 < 8; ++k2)
#pragma unroll
        for (int j = 0; j < CPL; ++j) {
            h2 t;
            t.x = (_Float16)Wae[(2 * k2) * H + c0 + j];
            t.y = (_Float16)Wae[(2 * k2 + 1) * H + c0 + j];
            w2h[k2][j] = t;
        }

    for (int v = blockIdx.x * NPB + wave * NPW + sub; v < N_NODES; v += gridDim.x * NPB) {
        // SL==64: v is wave-uniform; readfirstlane makes that provable so
        // row_ptr / srcs / e16 loads get scalar (SGPR) addressing.
        const int vv = (SL == 64) ? __builtin_amdgcn_readfirstlane(v) : v;
        float pd[CPL], acc[CPL];
        ld_f32<CPL>(&Pd[(size_t)vv * H + c0], pd);
#pragma unroll
        for (int j = 0; j < CPL; ++j) acc[j] = 0.f;
        const int p0 = row_ptr[vv], p1 = row_ptr[vv + 1];
        const int deg = p1 - p0;

        auto edge = [&](uint4 ra, uint4 rb, const float ps[CPL]) {
            union { u32 u; h2 h; } cv;
            h2 ev[8];
            cv.u = ra.x; ev[0] = cv.h; cv.u = ra.y; ev[1] = cv.h;
            cv.u = ra.z; ev[2] = cv.h; cv.u = ra.w; ev[3] = cv.h;
            cv.u = rb.x; ev[4] = cv.h; cv.u = rb.y; ev[5] = cv.h;
            cv.u = rb.z; ev[6] = cv.h; cv.u = rb.w; ev[7] = cv.h;
            float z[CPL];
#pragma unroll
            for (int j = 0; j < CPL; ++j) z[j] = pd[j] + ps[j];
#pragma unroll
            for (int k2 = 0; k2 < 8; ++k2)
#pragma unroll
                for (int j = 0; j < CPL; ++j) z[j] = DOT2(ev[k2], w2h[k2][j], z[j]);
#pragma unroll
            for (int j = 0; j < CPL; ++j) acc[j] += fmaxf(z[j], 0.f);
        };

        int p = p0;
        // 4-edge unroll: 4 independent srcs->Ps chains + 8 uint4 e16 loads in
        // flight per iteration (memory-level parallelism vs r11's 2).
        for (; p + 3 < p1; p += 4) {
            int s0 = srcs[p], s1 = srcs[p + 1], s2 = srcs[p + 2], s3 = srcs[p + 3];
            const uint4* e0 = (const uint4*)(e16s + (size_t)p * 16);
            uint4 a0 = e0[0], a1 = e0[1];
            uint4 b0 = e0[2], b1 = e0[3];
            uint4 g0 = e0[4], g1 = e0[5];
            uint4 d0 = e0[6], d1 = e0[7];
            float ps0[CPL], ps1[CPL], ps2[CPL], ps3[CPL];
            ld_bf16<CPL>(&Ps[(size_t)s0 * H + c0], ps0);
            ld_bf16<CPL>(&Ps[(size_t)s1 * H + c0], ps1);
            ld_bf16<CPL>(&Ps[(size_t)s2 * H + c0], ps2);
            ld_bf16<CPL>(&Ps[(size_t)s3 * H + c0], ps3);
            edge(a0, a1, ps0);
            edge(b0, b1, ps1);
            edge(g0, g1, ps2);
            edge(d0, d1, ps3);
        }
        for (; p < p1; ++p) {
            int s0 = srcs[p];
            const uint4* e0 = (const uint4*)(e16s + (size_t)p * 16);
            uint4 a0 = e0[0], a1 = e0[1];
            float ps0[CPL];
            ld_bf16<CPL>(&Ps[(size_t)s0 * H + c0], ps0);
            edge(a0, a1, ps0);
        }

        // mean; write m back into Pd[v] (only this wave ever touches Pd[v])
        const float invd = (deg > 0) ? 1.f / (float)deg : 0.f;
        if constexpr (CPL == 2) {
            float2 o; o.x = acc[0] * invd; o.y = acc[1] * invd;
            *(float2*)&Pd[(size_t)vv * H + c0] = o;
        } else {
            Pd[(size_t)vv * H + c0] = acc[0] * invd;
        }
    }
}

// ---------------- y = m @ Wb + bb (deg>0 mask), streaming ----------------
template <int H, int Fo>
__global__ __launch_bounds__(256) void matvec_k(const float* __restrict__ m,
        const int* __restrict__ row_ptr,
        const float* __restrict__ Wb, const float* __restrict__ bb,
        float* __restrict__ y) {
    __shared__ float Wb_sh[H * Fo];
    for (int i = threadIdx.x; i < H * Fo; i += 256) Wb_sh[i] = Wb[i];
    __syncthreads();
    int idx = blockIdx.x * 256 + threadIdx.x;
    if (idx >= N_NODES * Fo) return;
    int v = idx / Fo, c = idx % Fo;
    const int deg = row_ptr[v + 1] - row_ptr[v];
    const float* mr = m + (size_t)v * H;
    float acc = bb[c];
#pragma unroll 4
    for (int k = 0; k < H; k += 4) {
        float4 mv = *(const float4*)(mr + k);
        acc += mv.x * Wb_sh[k * Fo + c] + mv.y * Wb_sh[(k + 1) * Fo + c]
             + mv.z * Wb_sh[(k + 2) * Fo + c] + mv.w * Wb_sh[(k + 3) * Fo + c];
    }
    y[idx] = (deg > 0) ? acc : 0.f;
}

// ---------------- BN stats + normalize ----------------
template <int Fo>
__global__ __launch_bounds__(256) void stats2_k(const float* __restrict__ y, float* __restrict__ stats) {
    __shared__ float sh[2 * Fo];
    for (int i = threadIdx.x; i < 2 * Fo; i += 256) sh[i] = 0.f;
    __syncthreads();
    const int co = threadIdx.x % Fo;
    float s1 = 0.f, s2 = 0.f;
    const long long total = (long long)N_NODES * Fo;
    for (long long i = (long long)blockIdx.x * 256 + threadIdx.x; i < total; i += (long long)gridDim.x * 256) {
        float v = y[i];
        s1 += v; s2 += v * v;
    }
    atomicAdd(&sh[co], s1);
    atomicAdd(&sh[Fo + co], s2);
    __syncthreads();
    if (threadIdx.x < 2 * Fo) atomicAdd(&stats[threadIdx.x], sh[threadIdx.x]);
}

template <int Fo>
__global__ __launch_bounds__(256) void bnrelu_k(float* __restrict__ y,
        const float* __restrict__ stats, const float* __restrict__ g, const float* __restrict__ beta) {
    int idx = blockIdx.x * 256 + threadIdx.x;
    if (idx >= N_NODES * Fo) return;
    int co = idx % Fo;
    const float invN = 1.0f / (float)N_NODES;
    float mu = stats[co] * invN;
    float ex2 = stats[Fo + co] * invN;
    float var = fmaxf(ex2 - mu * mu, 0.f);
    float rs = rsqrtf(var + 1e-5f);
    y[idx] = fmaxf((y[idx] - mu) * rs * g[co] + beta[co], 0.f);
}

// ---------------- pooling & head ----------------
__global__ __launch_bounds__(256) void pool_k(const float* __restrict__ h,
        const int* __restrict__ batch, float* __restrict__ pool, int* __restrict__ gcnt) {
    int idx = blockIdx.x * 256 + threadIdx.x;
    if (idx >= N_NODES * 16) return;
    int v = idx >> 4, c = idx & 15;
    int b = batch[v];
    atomicAdd(&pool[b * 16 + c], h[idx]);
    if (c == 0) atomicAdd(&gcnt[b], 1);
}

__global__ __launch_bounds__(256) void out_k(const float* __restrict__ pool,
        const int* __restrict__ gcnt, const float* __restrict__ Wfc,
        const float* __restrict__ bfc, float* __restrict__ out) {
    int idx = blockIdx.x * 256 + threadIdx.x;
    if (idx >= NUM_GRAPHS * 12) return;
    int g = idx / 12, o = idx % 12;
    int cnt = gcnt[g];
    float inv = 1.0f / (float)(cnt > 0 ? cnt : 1);
    float acc = bfc[o];
#pragma unroll
    for (int k = 0; k < 16; ++k) acc += pool[g * 16 + k] * inv * Wfc[k * 12 + o];
    out[idx] = 1.0f / (1.0f + expf(-acc));
}

extern "C" void kernel_launch(void* const* d_in, const int* in_sizes, int n_in,
                              void* d_out, int out_size, void* d_ws, size_t ws_size,
                              hipStream_t stream) {
    const size_t N = N_NODES, E = N_EDGES, G = NUM_GRAPHS;
    const float* x = (const float*)d_in[0];
    const float* ea = (const float*)d_in[1];
    const int* ei = (const int*)d_in[2];
    const int* srcv = ei;
    const int* dstv = ei + E;
    const int* batch = (const int*)d_in[3];
    const float* Wn = (const float*)d_in[5];  const float* bn_ = (const float*)d_in[6];
    const float* We = (const float*)d_in[7];  const float* be_ = (const float*)d_in[8];
    const float* W1a = (const float*)d_in[9]; const float* b1a = (const float*)d_in[10];
    const float* W1b = (const float*)d_in[11]; const float* b1b = (const float*)d_in[12];
    const float* W2a = (const float*)d_in[13]; const float* b2a = (const float*)d_in[14];
    const float* W2b = (const float*)d_in[15]; const float* b2b = (const float*)d_in[16];
    const float* W3a = (const float*)d_in[17]; const float* b3a = (const float*)d_in[18];
    const float* W3b = (const float*)d_in[19]; const float* b3b = (const float*)d_in[20];
    const float* g1 = (const float*)d_in[21]; const float* be1 = (const float*)d_in[22];
    const float* g2 = (const float*)d_in[23]; const float* be2 = (const float*)d_in[24];
    const float* g3 = (const float*)d_in[25]; const float* be3 = (const float*)d_in[26];
    const float* Wfc = (const float*)d_in[27]; const float* bfc = (const float*)d_in[28];

    char* base = (char*)d_ws;
    size_t off = 0;
    auto take = [&](size_t bytes) { size_t o = off; off += (bytes + 255) & ~(size_t)255; return o; };
    int* hist = (int*)(base + take(N * 4));
    int* cursor = (int*)(base + take(N * 4));
    int* row_ptr = (int*)(base + take((N + 1) * 4));
    int* bsum = (int*)(base + take(256 * 4));
    int* boff = (int*)(base + take(256 * 4));
    int* sorted = (int*)(base + take(E * 4));
    int* srcs = (int*)(base + take(E * 4));
    float* hbuf = (float*)(base + take(N * 64 * 4));
    float* Pd = (float*)(base + take(N * 128 * 4));
    u16* Ps = (u16*)(base + take(N * 128 * 2));
    _Float16* e16s = (_Float16*)(base + take(E * 16 * 2));
    float* stats = (float*)(base + take(256 * 4));
    float* pool = (float*)(base + take(G * 16 * 4));
    int* gcnt = (int*)(base + take(G * 4));
    if (off > ws_size) {
        fprintf(stderr, "kernel_launch: ws too small: need %zu have %zu\n", off, ws_size);
        return;
    }

    const int NB = (N_NODES + 1023) / 1024;

    // CSR build (+ srcs in sorted order)
    hipMemsetAsync(hist, 0, N * 4, stream);
    hist_k<<<dim3((E + 255) / 256), dim3(256), 0, stream>>>(dstv, hist);
    scan_part_k<<<dim3(NB), dim3(256), 0, stream>>>(hist, cursor, bsum);
    scan_top_k<<<dim3(1), dim3(256), 0, stream>>>(bsum, boff, NB, &row_ptr[N_NODES]);
    scan_add_k<<<dim3((N + 255) / 256), dim3(256), 0, stream>>>(cursor, boff, row_ptr, cursor);
    scatter_k<<<dim3((E + 255) / 256), dim3(256), 0, stream>>>(srcv, dstv, cursor, sorted, srcs);

    // embeddings (e16 f16, CSR order)
    edge_emb_k<<<dim3((E * 16 + 255) / 256), dim3(256), 0, stream>>>(ea, We, be_, sorted, e16s);
    node_emb_k<<<dim3((N * 64 + 255) / 256), dim3(256), 0, stream>>>(x, Wn, bn_, hbuf);

    // conv1: F=64, H=128, Fo=64
    proj_k<64, 128><<<dim3((N * 128 + 255) / 256), dim3(256), 0, stream>>>(hbuf, W1a, b1a, Pd, Ps);
    conv_k<128><<<dim3(3072), dim3(256), 0, stream>>>(row_ptr, srcs, e16s, Pd, Ps, W1a + 128 * 128);
    matvec_k<128, 64><<<dim3((N * 64 + 255) / 256), dim3(256), 0, stream>>>(Pd, row_ptr, W1b, b1b, hbuf);
    hipMemsetAsync(stats, 0, 256 * 4, stream);
    stats2_k<64><<<dim3(512), dim3(256), 0, stream>>>(hbuf, stats);
    bnrelu_k<64><<<dim3((N * 64 + 255) / 256), dim3(256), 0, stream>>>(hbuf, stats, g1, be1);

    // conv2: F=64, H=64, Fo=32
    proj_k<64, 64><<<dim3((N * 64 + 255) / 256), dim3(256), 0, stream>>>(hbuf, W2a, b2a, Pd, Ps);
    conv_k<64><<<dim3(3072), dim3(256), 0, stream>>>(row_ptr, srcs, e16s, Pd, Ps, W2a + 128 * 64);
    matvec_k<64, 32><<<dim3((N * 32 + 255) / 256), dim3(256), 0, stream>>>(Pd, row_ptr, W2b, b2b, hbuf);
    hipMemsetAsync(stats, 0, 256 * 4, stream);
    stats2_k<32><<<dim3(512), dim3(256), 0, stream>>>(hbuf, stats);
    bnrelu_k<32><<<dim3((N * 32 + 255) / 256), dim3(256), 0, stream>>>(hbuf, stats, g2, be2);

    // conv3: F=32, H=32, Fo=16 (2 nodes/wave)
    proj_k<32, 32><<<dim3((N * 32 + 255) / 256), dim3(256), 0, stream>>>(hbuf, W3a, b3a, Pd, Ps);
    conv_k<32><<<dim3(3072), dim3(256), 0, stream>>>(row_ptr, srcs, e16s, Pd, Ps, W3a + 64 * 32);
    matvec_k<32, 16><<<dim3((N * 16 + 255) / 256), dim3(256), 0, stream>>>(Pd, row_ptr, W3b, b3b, hbuf);
    hipMemsetAsync(stats, 0, 256 * 4, stream);
    stats2_k<16><<<dim3(512), dim3(256), 0, stream>>>(hbuf, stats);
    bnrelu_k<16><<<dim3((N * 16 + 255) / 256), dim3(256), 0, stream>>>(hbuf, stats, g3, be3);

    // pool + head
    hipMemsetAsync(pool, 0, G * 16 * 4, stream);
    hipMemsetAsync(gcnt, 0, G * 4, stream);
    pool_k<<<dim3((N * 16 + 255) / 256), dim3(256), 0, stream>>>(hbuf, batch, pool, gcnt);
    out_k<<<dim3((G * 12 + 255) / 256), dim3(256), 0, stream>>>(pool, gcnt, Wfc, bfc, (float*)d_out);
}

// Round 2
// 1136.110 us; speedup vs baseline: 1.5663x; 1.2826x over previous
//
#include <hip/hip_runtime.h>
#include <hip/hip_bf16.h>
#include <cstdio>

// GCNTox21 — round 13. r12 counters: proj_k<64,128> now #1 at 295us with
// VALUBusy 15%, HBM 3.8%, occ 85%, VGPR=20 -> latency/L1-issue bound GEMM
// (3 loads per 2 FMAs, Wa re-read per node, 64-deep serial FMA chains).
// Fix: proj_k rewritten as register-weight-cached broadcast GEMM:
//   - thread owns ONE output channel c of the fused 2H-channel output
//     (Pd channels [0,H), Ps channels [H,2H)) and register-caches its
//     64-float Wa column (zero Wa re-reads in the node loop).
//   - node tile (16 nodes per node-group) staged in LDS coalesced once;
//     inner loop = wave-uniform broadcast ds_read_b128 + 4 indep FMA chains.
//   - per node per thread: 16 LDS b128 + 64 FMA, no global loads.
// Everything else identical to r12 (conv_k gather/mean in-place into Pd,
// matvec_k epilogue, CSR build, plain __launch_bounds__(256)).

#define N_NODES 100000
#define N_EDGES 1600000
#define NUM_GRAPHS 4096

typedef unsigned short u16;
typedef unsigned int u32;
typedef _Float16 h2 __attribute__((ext_vector_type(2)));

#if defined(__has_builtin)
#if __has_builtin(__builtin_amdgcn_fdot2)
#define DOT2(a, b, c) __builtin_amdgcn_fdot2((a), (b), (c), false)
#endif
#endif
#ifndef DOT2
#define DOT2(a, b, c) ((c) + (float)(a).x * (float)(b).x + (float)(a).y * (float)(b).y)
#endif

__device__ __forceinline__ float b2f(u16 u) { union { u32 i; float f; } c; c.i = ((u32)u) << 16; return c.f; }
__device__ __forceinline__ float b2f_lo(u32 u) { union { u32 i; float f; } c; c.i = u << 16; return c.f; }
__device__ __forceinline__ float b2f_hi(u32 u) { union { u32 i; float f; } c; c.i = u & 0xffff0000u; return c.f; }
__device__ __forceinline__ u16 f2b(float f) {
    __hip_bfloat16 h = __float2bfloat16(f);
    return *reinterpret_cast<u16*>(&h);
}

template <int CPL>
__device__ __forceinline__ void ld_bf16(const u16* base, float out[CPL]) {
    if constexpr (CPL == 1) {
        out[0] = b2f(*base);
    } else {
        u32 v = *(const u32*)base;
        out[0] = b2f_lo(v); out[1] = b2f_hi(v);
    }
}
template <int CPL>
__device__ __forceinline__ void ld_f32(const float* base, float out[CPL]) {
    if constexpr (CPL == 1) {
        out[0] = *base;
    } else {
        float2 v = *(const float2*)base;
        out[0] = v.x; out[1] = v.y;
    }
}

// ---------------- CSR build ----------------
__global__ __launch_bounds__(256) void hist_k(const int* __restrict__ dst, int* __restrict__ hist) {
    int e = blockIdx.x * 256 + threadIdx.x;
    if (e < N_EDGES) atomicAdd(&hist[dst[e]], 1);
}

__global__ __launch_bounds__(256) void scan_part_k(const int* __restrict__ hist,
        int* __restrict__ excl, int* __restrict__ bsum) {
    __shared__ int sm[256];
    int t = threadIdx.x, b = blockIdx.x;
    int base = b * 1024 + t * 4;
    int v0 = (base + 0 < N_NODES) ? hist[base + 0] : 0;
    int v1 = (base + 1 < N_NODES) ? hist[base + 1] : 0;
    int v2 = (base + 2 < N_NODES) ? hist[base + 2] : 0;
    int v3 = (base + 3 < N_NODES) ? hist[base + 3] : 0;
    int tsum = v0 + v1 + v2 + v3;
    sm[t] = tsum;
    __syncthreads();
    for (int o = 1; o < 256; o <<= 1) {
        int x = (t >= o) ? sm[t - o] : 0;
        __syncthreads();
        sm[t] += x;
        __syncthreads();
    }
    int texcl = sm[t] - tsum;
    if (base + 0 < N_NODES) excl[base + 0] = texcl;
    if (base + 1 < N_NODES) excl[base + 1] = texcl + v0;
    if (base + 2 < N_NODES) excl[base + 2] = texcl + v0 + v1;
    if (base + 3 < N_NODES) excl[base + 3] = texcl + v0 + v1 + v2;
    if (t == 255) bsum[b] = sm[255];
}

__global__ __launch_bounds__(256) void scan_top_k(int* __restrict__ bsum, int* __restrict__ boff,
        int nb, int* __restrict__ row_ptr_last) {
    __shared__ int sm[256];
    int t = threadIdx.x;
    int v = (t < nb) ? bsum[t] : 0;
    sm[t] = v;
    __syncthreads();
    for (int o = 1; o < 256; o <<= 1) {
        int x = (t >= o) ? sm[t - o] : 0;
        __syncthreads();
        sm[t] += x;
        __syncthreads();
    }
    if (t < nb) boff[t] = sm[t] - v;
    if (t == 0) *row_ptr_last = sm[255];
}

__global__ __launch_bounds__(256) void scan_add_k(int* __restrict__ excl, const int* __restrict__ boff,
        int* __restrict__ row_ptr, int* __restrict__ cursor) {
    int i = blockIdx.x * 256 + threadIdx.x;
    if (i >= N_NODES) return;
    int s = excl[i] + boff[i >> 10];
    row_ptr[i] = s;
    cursor[i] = s;
}

__global__ __launch_bounds__(256) void scatter_k(const int* __restrict__ src, const int* __restrict__ dst,
        int* __restrict__ cursor, int* __restrict__ sorted_eid, int* __restrict__ srcs) {
    int e = blockIdx.x * 256 + threadIdx.x;
    if (e < N_EDGES) {
        int p = atomicAdd(&cursor[dst[e]], 1);
        sorted_eid[p] = e;
        srcs[p] = src[e];
    }
}

// ---------------- embeddings ----------------
__global__ __launch_bounds__(256) void edge_emb_k(const float* __restrict__ ea,
        const float* __restrict__ We, const float* __restrict__ be,
        const int* __restrict__ sorted_eid, _Float16* __restrict__ e16s) {
    int idx = blockIdx.x * 256 + threadIdx.x;
    if (idx >= N_EDGES * 16) return;
    int p = idx >> 4, k = idx & 15;
    int e = sorted_eid[p];
    float acc = be[k];
#pragma unroll
    for (int j = 0; j < 8; ++j) acc += ea[(size_t)e * 8 + j] * We[j * 16 + k];
    e16s[idx] = (_Float16)fmaxf(acc, 0.f);
}

__global__ __launch_bounds__(256) void node_emb_k(const float* __restrict__ x,
        const float* __restrict__ Wn, const float* __restrict__ bn_, float* __restrict__ h) {
    int idx = blockIdx.x * 256 + threadIdx.x;
    if (idx >= N_NODES * 64) return;
    int v = idx >> 6, c = idx & 63;
    float acc = bn_[c];
    for (int k = 0; k < 32; ++k) acc += x[(size_t)v * 32 + k] * Wn[(size_t)k * 64 + c];
    h[idx] = fmaxf(acc, 0.f);
}

// ---------------- projections: Pd fp32, Ps bf16 ----------------
// Register-weight-cached broadcast GEMM. Thread owns one of 2H fused output
// channels; Wa column lives in VGPRs; node tiles staged in LDS.
template <int F, int H>
__global__ __launch_bounds__(256) void proj_k(const float* __restrict__ h,
        const float* __restrict__ Wa, const float* __restrict__ ba,
        float* __restrict__ Pd, u16* __restrict__ Ps) {
    constexpr int C2 = 2 * H;            // fused output channels per node
    constexpr int NPB = 256 / C2;        // node subgroups per block: 1/2/4
    constexpr int TILE = 16 * NPB;       // nodes staged per tile
    __shared__ float hs[TILE][F];        // 4KB / 8KB / 8KB
    const int t = threadIdx.x;
    const int grp = t / C2;
    const int c = t % C2;
    const bool is_src = (c >= H);
    const int cc = is_src ? (c - H) : c;
    // register-cache weight column Wa[(is_src?F:0)+k][cc]
    float w[F];
    const float* wcol = Wa + (size_t)(is_src ? F : 0) * H + cc;
#pragma unroll
    for (int k = 0; k < F; ++k) w[k] = wcol[(size_t)k * H];
    const float bias = is_src ? 0.f : ba[cc];

    for (int v0 = blockIdx.x * TILE; v0 < N_NODES; v0 += gridDim.x * TILE) {
        __syncthreads();
        for (int i = t; i < TILE * F; i += 256) {
            int vv = v0 + i / F;
            hs[i / F][i % F] = (vv < N_NODES) ? h[(size_t)vv * F + (i % F)] : 0.f;
        }
        __syncthreads();
        const int base = grp * 16;
        const int nmax = (N_NODES - v0 - base >= 16) ? 16
                        : (N_NODES - v0 - base > 0 ? N_NODES - v0 - base : 0);
#pragma unroll 2
        for (int n = 0; n < nmax; ++n) {
            const int v = v0 + base + n;
            const float4* hr4 = (const float4*)hs[base + n];
            float a0 = bias, a1 = 0.f, a2 = 0.f, a3 = 0.f;
#pragma unroll
            for (int k4 = 0; k4 < F / 4; ++k4) {
                float4 hv = hr4[k4];
                a0 += hv.x * w[4 * k4 + 0];
                a1 += hv.y * w[4 * k4 + 1];
                a2 += hv.z * w[4 * k4 + 2];
                a3 += hv.w * w[4 * k4 + 3];
            }
            float acc = (a0 + a1) + (a2 + a3);
            if (is_src) Ps[(size_t)v * H + cc] = f2b(acc);
            else        Pd[(size_t)v * H + cc] = acc;
        }
    }
}

// ---------------- fused conv: CSR gather + mean; writes m into Pd in place --
template <int H>
__global__ __launch_bounds__(256) void conv_k(
        const int* __restrict__ row_ptr, const int* __restrict__ srcs,
        const _Float16* __restrict__ e16s,
        float* __restrict__ Pd, const u16* __restrict__ Ps,
        const float* __restrict__ Wae) {
    constexpr int SL = (H >= 64) ? 64 : 32;   // lanes per node
    constexpr int NPW = 64 / SL;              // nodes per wave
    constexpr int CPL = H / SL;               // channels per lane
    constexpr int NPB = 4 * NPW;              // nodes per block per iter
    const int wave = threadIdx.x >> 6, lane = threadIdx.x & 63;
    const int sub = lane / SL;
    const int sl = lane % SL;
    const int c0 = sl * CPL;
    h2 w2h[8][CPL];
#pragma unroll
    for (int k2 = 0; k2 < 8; ++k2)
#pragma unroll
        for (int j = 0; j < CPL; ++j) {
            h2 t;
            t.x = (_Float16)Wae[(2 * k2) * H + c0 + j];
            t.y = (_Float16)Wae[(2 * k2 + 1) * H + c0 + j];
            w2h[k2][j] = t;
        }

    for (int v = blockIdx.x * NPB + wave * NPW + sub; v < N_NODES; v += gridDim.x * NPB) {
        // SL==64: v is wave-uniform; readfirstlane makes that provable so
        // row_ptr / srcs / e16 loads get scalar (SGPR) addressing.
        const int vv = (SL == 64) ? __builtin_amdgcn_readfirstlane(v) : v;
        float pd[CPL], acc[CPL];
        ld_f32<CPL>(&Pd[(size_t)vv * H + c0], pd);
#pragma unroll
        for (int j = 0; j < CPL; ++j) acc[j] = 0.f;
        const int p0 = row_ptr[vv], p1 = row_ptr[vv + 1];
        const int deg = p1 - p0;

        auto edge = [&](uint4 ra, uint4 rb, const float ps[CPL]) {
            union { u32 u; h2 h; } cv;
            h2 ev[8];
            cv.u = ra.x; ev[0] = cv.h; cv.u = ra.y; ev[1] = cv.h;
            cv.u = ra.z; ev[2] = cv.h; cv.u = ra.w; ev[3] = cv.h;
            cv.u = rb.x; ev[4] = cv.h; cv.u = rb.y; ev[5] = cv.h;
            cv.u = rb.z; ev[6] = cv.h; cv.u = rb.w; ev[7] = cv.h;
            float z[CPL];
#pragma unroll
            for (int j = 0; j < CPL; ++j) z[j] = pd[j] + ps[j];
#pragma unroll
            for (int k2 = 0; k2 < 8; ++k2)
#pragma unroll
                for (int j = 0; j < CPL; ++j) z[j] = DOT2(ev[k2], w2h[k2][j], z[j]);
#pragma unroll
            for (int j = 0; j < CPL; ++j) acc[j] += fmaxf(z[j], 0.f);
        };

        int p = p0;
        // 4-edge unroll: 4 independent srcs->Ps chains + 8 uint4 e16 loads in
        // flight per iteration.
        for (; p + 3 < p1; p += 4) {
            int s0 = srcs[p], s1 = srcs[p + 1], s2 = srcs[p + 2], s3 = srcs[p + 3];
            const uint4* e0 = (const uint4*)(e16s + (size_t)p * 16);
            uint4 a0 = e0[0], a1 = e0[1];
            uint4 b0 = e0[2], b1 = e0[3];
            uint4 g0 = e0[4], g1 = e0[5];
            uint4 d0 = e0[6], d1 = e0[7];
            float ps0[CPL], ps1[CPL], ps2[CPL], ps3[CPL];
            ld_bf16<CPL>(&Ps[(size_t)s0 * H + c0], ps0);
            ld_bf16<CPL>(&Ps[(size_t)s1 * H + c0], ps1);
            ld_bf16<CPL>(&Ps[(size_t)s2 * H + c0], ps2);
            ld_bf16<CPL>(&Ps[(size_t)s3 * H + c0], ps3);
            edge(a0, a1, ps0);
            edge(b0, b1, ps1);
            edge(g0, g1, ps2);
            edge(d0, d1, ps3);
        }
        for (; p < p1; ++p) {
            int s0 = srcs[p];
            const uint4* e0 = (const uint4*)(e16s + (size_t)p * 16);
            uint4 a0 = e0[0], a1 = e0[1];
            float ps0[CPL];
            ld_bf16<CPL>(&Ps[(size_t)s0 * H + c0], ps0);
            edge(a0, a1, ps0);
        }

        // mean; write m back into Pd[v] (only this wave ever touches Pd[v])
        const float invd = (deg > 0) ? 1.f / (float)deg : 0.f;
        if constexpr (CPL == 2) {
            float2 o; o.x = acc[0] * invd; o.y = acc[1] * invd;
            *(float2*)&Pd[(size_t)vv * H + c0] = o;
        } else {
            Pd[(size_t)vv * H + c0] = acc[0] * invd;
        }
    }
}

// ---------------- y = m @ Wb + bb (deg>0 mask), streaming ----------------
template <int H, int Fo>
__global__ __launch_bounds__(256) void matvec_k(const float* __restrict__ m,
        const int* __restrict__ row_ptr,
        const float* __restrict__ Wb, const float* __restrict__ bb,
        float* __restrict__ y) {
    __shared__ float Wb_sh[H * Fo];
    for (int i = threadIdx.x; i < H * Fo; i += 256) Wb_sh[i] = Wb[i];
    __syncthreads();
    int idx = blockIdx.x * 256 + threadIdx.x;
    if (idx >= N_NODES * Fo) return;
    int v = idx / Fo, c = idx % Fo;
    const int deg = row_ptr[v + 1] - row_ptr[v];
    const float* mr = m + (size_t)v * H;
    float acc = bb[c];
#pragma unroll 4
    for (int k = 0; k < H; k += 4) {
        float4 mv = *(const float4*)(mr + k);
        acc += mv.x * Wb_sh[k * Fo + c] + mv.y * Wb_sh[(k + 1) * Fo + c]
             + mv.z * Wb_sh[(k + 2) * Fo + c] + mv.w * Wb_sh[(k + 3) * Fo + c];
    }
    y[idx] = (deg > 0) ? acc : 0.f;
}

// ---------------- BN stats + normalize ----------------
template <int Fo>
__global__ __launch_bounds__(256) void stats2_k(const float* __restrict__ y, float* __restrict__ stats) {
    __shared__ float sh[2 * Fo];
    for (int i = threadIdx.x; i < 2 * Fo; i += 256) sh[i] = 0.f;
    __syncthreads();
    const int co = threadIdx.x % Fo;
    float s1 = 0.f, s2 = 0.f;
    const long long total = (long long)N_NODES * Fo;
    for (long long i = (long long)blockIdx.x * 256 + threadIdx.x; i < total; i += (long long)gridDim.x * 256) {
        float v = y[i];
        s1 += v; s2 += v * v;
    }
    atomicAdd(&sh[co], s1);
    atomicAdd(&sh[Fo + co], s2);
    __syncthreads();
    if (threadIdx.x < 2 * Fo) atomicAdd(&stats[threadIdx.x], sh[threadIdx.x]);
}

template <int Fo>
__global__ __launch_bounds__(256) void bnrelu_k(float* __restrict__ y,
        const float* __restrict__ stats, const float* __restrict__ g, const float* __restrict__ beta) {
    int idx = blockIdx.x * 256 + threadIdx.x;
    if (idx >= N_NODES * Fo) return;
    int co = idx % Fo;
    const float invN = 1.0f / (float)N_NODES;
    float mu = stats[co] * invN;
    float ex2 = stats[Fo + co] * invN;
    float var = fmaxf(ex2 - mu * mu, 0.f);
    float rs = rsqrtf(var + 1e-5f);
    y[idx] = fmaxf((y[idx] - mu) * rs * g[co] + beta[co], 0.f);
}

// ---------------- pooling & head ----------------
__global__ __launch_bounds__(256) void pool_k(const float* __restrict__ h,
        const int* __restrict__ batch, float* __restrict__ pool, int* __restrict__ gcnt) {
    int idx = blockIdx.x * 256 + threadIdx.x;
    if (idx >= N_NODES * 16) return;
    int v = idx >> 4, c = idx & 15;
    int b = batch[v];
    atomicAdd(&pool[b * 16 + c], h[idx]);
    if (c == 0) atomicAdd(&gcnt[b], 1);
}

__global__ __launch_bounds__(256) void out_k(const float* __restrict__ pool,
        const int* __restrict__ gcnt, const float* __restrict__ Wfc,
        const float* __restrict__ bfc, float* __restrict__ out) {
    int idx = blockIdx.x * 256 + threadIdx.x;
    if (idx >= NUM_GRAPHS * 12) return;
    int g = idx / 12, o = idx % 12;
    int cnt = gcnt[g];
    float inv = 1.0f / (float)(cnt > 0 ? cnt : 1);
    float acc = bfc[o];
#pragma unroll
    for (int k = 0; k < 16; ++k) acc += pool[g * 16 + k] * inv * Wfc[k * 12 + o];
    out[idx] = 1.0f / (1.0f + expf(-acc));
}

extern "C" void kernel_launch(void* const* d_in, const int* in_sizes, int n_in,
                              void* d_out, int out_size, void* d_ws, size_t ws_size,
                              hipStream_t stream) {
    const size_t N = N_NODES, E = N_EDGES, G = NUM_GRAPHS;
    const float* x = (const float*)d_in[0];
    const float* ea = (const float*)d_in[1];
    const int* ei = (const int*)d_in[2];
    const int* srcv = ei;
    const int* dstv = ei + E;
    const int* batch = (const int*)d_in[3];
    const float* Wn = (const float*)d_in[5];  const float* bn_ = (const float*)d_in[6];
    const float* We = (const float*)d_in[7];  const float* be_ = (const float*)d_in[8];
    const float* W1a = (const float*)d_in[9]; const float* b1a = (const float*)d_in[10];
    const float* W1b = (const float*)d_in[11]; const float* b1b = (const float*)d_in[12];
    const float* W2a = (const float*)d_in[13]; const float* b2a = (const float*)d_in[14];
    const float* W2b = (const float*)d_in[15]; const float* b2b = (const float*)d_in[16];
    const float* W3a = (const float*)d_in[17]; const float* b3a = (const float*)d_in[18];
    const float* W3b = (const float*)d_in[19]; const float* b3b = (const float*)d_in[20];
    const float* g1 = (const float*)d_in[21]; const float* be1 = (const float*)d_in[22];
    const float* g2 = (const float*)d_in[23]; const float* be2 = (const float*)d_in[24];
    const float* g3 = (const float*)d_in[25]; const float* be3 = (const float*)d_in[26];
    const float* Wfc = (const float*)d_in[27]; const float* bfc = (const float*)d_in[28];

    char* base = (char*)d_ws;
    size_t off = 0;
    auto take = [&](size_t bytes) { size_t o = off; off += (bytes + 255) & ~(size_t)255; return o; };
    int* hist = (int*)(base + take(N * 4));
    int* cursor = (int*)(base + take(N * 4));
    int* row_ptr = (int*)(base + take((N + 1) * 4));
    int* bsum = (int*)(base + take(256 * 4));
    int* boff = (int*)(base + take(256 * 4));
    int* sorted = (int*)(base + take(E * 4));
    int* srcs = (int*)(base + take(E * 4));
    float* hbuf = (float*)(base + take(N * 64 * 4));
    float* Pd = (float*)(base + take(N * 128 * 4));
    u16* Ps = (u16*)(base + take(N * 128 * 2));
    _Float16* e16s = (_Float16*)(base + take(E * 16 * 2));
    float* stats = (float*)(base + take(256 * 4));
    float* pool = (float*)(base + take(G * 16 * 4));
    int* gcnt = (int*)(base + take(G * 4));
    if (off > ws_size) {
        fprintf(stderr, "kernel_launch: ws too small: need %zu have %zu\n", off, ws_size);
        return;
    }

    const int NB = (N_NODES + 1023) / 1024;

    // CSR build (+ srcs in sorted order)
    hipMemsetAsync(hist, 0, N * 4, stream);
    hist_k<<<dim3((E + 255) / 256), dim3(256), 0, stream>>>(dstv, hist);
    scan_part_k<<<dim3(NB), dim3(256), 0, stream>>>(hist, cursor, bsum);
    scan_top_k<<<dim3(1), dim3(256), 0, stream>>>(bsum, boff, NB, &row_ptr[N_NODES]);
    scan_add_k<<<dim3((N + 255) / 256), dim3(256), 0, stream>>>(cursor, boff, row_ptr, cursor);
    scatter_k<<<dim3((E + 255) / 256), dim3(256), 0, stream>>>(srcv, dstv, cursor, sorted, srcs);

    // embeddings (e16 f16, CSR order)
    edge_emb_k<<<dim3((E * 16 + 255) / 256), dim3(256), 0, stream>>>(ea, We, be_, sorted, e16s);
    node_emb_k<<<dim3((N * 64 + 255) / 256), dim3(256), 0, stream>>>(x, Wn, bn_, hbuf);

    // conv1: F=64, H=128, Fo=64   (proj: TILE=16 -> 6250 blocks)
    proj_k<64, 128><<<dim3(6250), dim3(256), 0, stream>>>(hbuf, W1a, b1a, Pd, Ps);
    conv_k<128><<<dim3(3072), dim3(256), 0, stream>>>(row_ptr, srcs, e16s, Pd, Ps, W1a + 128 * 128);
    matvec_k<128, 64><<<dim3((N * 64 + 255) / 256), dim3(256), 0, stream>>>(Pd, row_ptr, W1b, b1b, hbuf);
    hipMemsetAsync(stats, 0, 256 * 4, stream);
    stats2_k<64><<<dim3(512), dim3(256), 0, stream>>>(hbuf, stats);
    bnrelu_k<64><<<dim3((N * 64 + 255) / 256), dim3(256), 0, stream>>>(hbuf, stats, g1, be1);

    // conv2: F=64, H=64, Fo=32    (proj: TILE=32 -> 3125 blocks)
    proj_k<64, 64><<<dim3(3125), dim3(256), 0, stream>>>(hbuf, W2a, b2a, Pd, Ps);
    conv_k<64><<<dim3(3072), dim3(256), 0, stream>>>(row_ptr, srcs, e16s, Pd, Ps, W2a + 128 * 64);
    matvec_k<64, 32><<<dim3((N * 32 + 255) / 256), dim3(256), 0, stream>>>(Pd, row_ptr, W2b, b2b, hbuf);
    hipMemsetAsync(stats, 0, 256 * 4, stream);
    stats2_k<32><<<dim3(512), dim3(256), 0, stream>>>(hbuf, stats);
    bnrelu_k<32><<<dim3((N * 32 + 255) / 256), dim3(256), 0, stream>>>(hbuf, stats, g2, be2);

    // conv3: F=32, H=32, Fo=16    (proj: TILE=64 -> 1563 blocks)
    proj_k<32, 32><<<dim3(1563), dim3(256), 0, stream>>>(hbuf, W3a, b3a, Pd, Ps);
    conv_k<32><<<dim3(3072), dim3(256), 0, stream>>>(row_ptr, srcs, e16s, Pd, Ps, W3a + 64 * 32);
    matvec_k<32, 16><<<dim3((N * 16 + 255) / 256), dim3(256), 0, stream>>>(Pd, row_ptr, W3b, b3b, hbuf);
    hipMemsetAsync(stats, 0, 256 * 4, stream);
    stats2_k<16><<<dim3(512), dim3(256), 0, stream>>>(hbuf, stats);
    bnrelu_k<16><<<dim3((N * 16 + 255) / 256), dim3(256), 0, stream>>>(hbuf, stats, g3, be3);

    // pool + head
    hipMemsetAsync(pool, 0, G * 16 * 4, stream);
    hipMemsetAsync(gcnt, 0, G * 4, stream);
    pool_k<<<dim3((N * 16 + 255) / 256), dim3(256), 0, stream>>>(hbuf, batch, pool, gcnt);
    out_k<<<dim3((G * 12 + 255) / 256), dim3(256), 0, stream>>>(pool, gcnt, Wfc, bfc, (float*)d_out);
}

// Round 3
// 1104.704 us; speedup vs baseline: 1.6108x; 1.0284x over previous
//
#include <hip/hip_runtime.h>
#include <hip/hip_bf16.h>
#include <cstdio>

// GCNTox21 — round 14. r13 counters: matvec_k<128,64> #1 at 139us, VALUBusy
// 39%, HBM 4.7%, occ 42% (32KB LDS cap), VGPR=44. Structure problem: each
// block staged 32KB Wb to compute only 4 nodes, 128 serial-chain FMAs fed by
// 128 ds_read_b32 per output.
// Fix: matvec_k rewritten like r13's proj_k win:
//   - lane owns one output channel c, register-caches its Wb column w[H]
//     (fully unrolled -> compile-time indices, no scratch),
//   - grid-stride over nodes (1024 blocks) so the one-time Wb load amortizes,
//   - per node: 32 broadcast float4 loads of m-row + 4 indep acc chains,
//     zero LDS in the hot loop,
//   - BN stats (sum, sumsq) accumulate in 2 registers per lane (channel is
//     fixed), flushed once per block via small LDS reduce + 1 atomic/channel
//     -> stats2_k deleted entirely.
// Everything else identical to r13.

#define N_NODES 100000
#define N_EDGES 1600000
#define NUM_GRAPHS 4096

typedef unsigned short u16;
typedef unsigned int u32;
typedef _Float16 h2 __attribute__((ext_vector_type(2)));

#if defined(__has_builtin)
#if __has_builtin(__builtin_amdgcn_fdot2)
#define DOT2(a, b, c) __builtin_amdgcn_fdot2((a), (b), (c), false)
#endif
#endif
#ifndef DOT2
#define DOT2(a, b, c) ((c) + (float)(a).x * (float)(b).x + (float)(a).y * (float)(b).y)
#endif

__device__ __forceinline__ float b2f(u16 u) { union { u32 i; float f; } c; c.i = ((u32)u) << 16; return c.f; }
__device__ __forceinline__ float b2f_lo(u32 u) { union { u32 i; float f; } c; c.i = u << 16; return c.f; }
__device__ __forceinline__ float b2f_hi(u32 u) { union { u32 i; float f; } c; c.i = u & 0xffff0000u; return c.f; }
__device__ __forceinline__ u16 f2b(float f) {
    __hip_bfloat16 h = __float2bfloat16(f);
    return *reinterpret_cast<u16*>(&h);
}

template <int CPL>
__device__ __forceinline__ void ld_bf16(const u16* base, float out[CPL]) {
    if constexpr (CPL == 1) {
        out[0] = b2f(*base);
    } else {
        u32 v = *(const u32*)base;
        out[0] = b2f_lo(v); out[1] = b2f_hi(v);
    }
}
template <int CPL>
__device__ __forceinline__ void ld_f32(const float* base, float out[CPL]) {
    if constexpr (CPL == 1) {
        out[0] = *base;
    } else {
        float2 v = *(const float2*)base;
        out[0] = v.x; out[1] = v.y;
    }
}

// ---------------- CSR build ----------------
__global__ __launch_bounds__(256) void hist_k(const int* __restrict__ dst, int* __restrict__ hist) {
    int e = blockIdx.x * 256 + threadIdx.x;
    if (e < N_EDGES) atomicAdd(&hist[dst[e]], 1);
}

__global__ __launch_bounds__(256) void scan_part_k(const int* __restrict__ hist,
        int* __restrict__ excl, int* __restrict__ bsum) {
    __shared__ int sm[256];
    int t = threadIdx.x, b = blockIdx.x;
    int base = b * 1024 + t * 4;
    int v0 = (base + 0 < N_NODES) ? hist[base + 0] : 0;
    int v1 = (base + 1 < N_NODES) ? hist[base + 1] : 0;
    int v2 = (base + 2 < N_NODES) ? hist[base + 2] : 0;
    int v3 = (base + 3 < N_NODES) ? hist[base + 3] : 0;
    int tsum = v0 + v1 + v2 + v3;
    sm[t] = tsum;
    __syncthreads();
    for (int o = 1; o < 256; o <<= 1) {
        int x = (t >= o) ? sm[t - o] : 0;
        __syncthreads();
        sm[t] += x;
        __syncthreads();
    }
    int texcl = sm[t] - tsum;
    if (base + 0 < N_NODES) excl[base + 0] = texcl;
    if (base + 1 < N_NODES) excl[base + 1] = texcl + v0;
    if (base + 2 < N_NODES) excl[base + 2] = texcl + v0 + v1;
    if (base + 3 < N_NODES) excl[base + 3] = texcl + v0 + v1 + v2;
    if (t == 255) bsum[b] = sm[255];
}

__global__ __launch_bounds__(256) void scan_top_k(int* __restrict__ bsum, int* __restrict__ boff,
        int nb, int* __restrict__ row_ptr_last) {
    __shared__ int sm[256];
    int t = threadIdx.x;
    int v = (t < nb) ? bsum[t] : 0;
    sm[t] = v;
    __syncthreads();
    for (int o = 1; o < 256; o <<= 1) {
        int x = (t >= o) ? sm[t - o] : 0;
        __syncthreads();
        sm[t] += x;
        __syncthreads();
    }
    if (t < nb) boff[t] = sm[t] - v;
    if (t == 0) *row_ptr_last = sm[255];
}

__global__ __launch_bounds__(256) void scan_add_k(int* __restrict__ excl, const int* __restrict__ boff,
        int* __restrict__ row_ptr, int* __restrict__ cursor) {
    int i = blockIdx.x * 256 + threadIdx.x;
    if (i >= N_NODES) return;
    int s = excl[i] + boff[i >> 10];
    row_ptr[i] = s;
    cursor[i] = s;
}

__global__ __launch_bounds__(256) void scatter_k(const int* __restrict__ src, const int* __restrict__ dst,
        int* __restrict__ cursor, int* __restrict__ sorted_eid, int* __restrict__ srcs) {
    int e = blockIdx.x * 256 + threadIdx.x;
    if (e < N_EDGES) {
        int p = atomicAdd(&cursor[dst[e]], 1);
        sorted_eid[p] = e;
        srcs[p] = src[e];
    }
}

// ---------------- embeddings ----------------
__global__ __launch_bounds__(256) void edge_emb_k(const float* __restrict__ ea,
        const float* __restrict__ We, const float* __restrict__ be,
        const int* __restrict__ sorted_eid, _Float16* __restrict__ e16s) {
    int idx = blockIdx.x * 256 + threadIdx.x;
    if (idx >= N_EDGES * 16) return;
    int p = idx >> 4, k = idx & 15;
    int e = sorted_eid[p];
    float acc = be[k];
#pragma unroll
    for (int j = 0; j < 8; ++j) acc += ea[(size_t)e * 8 + j] * We[j * 16 + k];
    e16s[idx] = (_Float16)fmaxf(acc, 0.f);
}

__global__ __launch_bounds__(256) void node_emb_k(const float* __restrict__ x,
        const float* __restrict__ Wn, const float* __restrict__ bn_, float* __restrict__ h) {
    int idx = blockIdx.x * 256 + threadIdx.x;
    if (idx >= N_NODES * 64) return;
    int v = idx >> 6, c = idx & 63;
    float acc = bn_[c];
    for (int k = 0; k < 32; ++k) acc += x[(size_t)v * 32 + k] * Wn[(size_t)k * 64 + c];
    h[idx] = fmaxf(acc, 0.f);
}

// ---------------- projections: Pd fp32, Ps bf16 ----------------
// Register-weight-cached broadcast GEMM. Thread owns one of 2H fused output
// channels; Wa column lives in VGPRs; node tiles staged in LDS.
template <int F, int H>
__global__ __launch_bounds__(256) void proj_k(const float* __restrict__ h,
        const float* __restrict__ Wa, const float* __restrict__ ba,
        float* __restrict__ Pd, u16* __restrict__ Ps) {
    constexpr int C2 = 2 * H;            // fused output channels per node
    constexpr int NPB = 256 / C2;        // node subgroups per block: 1/2/4
    constexpr int TILE = 16 * NPB;       // nodes staged per tile
    __shared__ float hs[TILE][F];        // 4KB / 8KB / 8KB
    const int t = threadIdx.x;
    const int grp = t / C2;
    const int c = t % C2;
    const bool is_src = (c >= H);
    const int cc = is_src ? (c - H) : c;
    // register-cache weight column Wa[(is_src?F:0)+k][cc]
    float w[F];
    const float* wcol = Wa + (size_t)(is_src ? F : 0) * H + cc;
#pragma unroll
    for (int k = 0; k < F; ++k) w[k] = wcol[(size_t)k * H];
    const float bias = is_src ? 0.f : ba[cc];

    for (int v0 = blockIdx.x * TILE; v0 < N_NODES; v0 += gridDim.x * TILE) {
        __syncthreads();
        for (int i = t; i < TILE * F; i += 256) {
            int vv = v0 + i / F;
            hs[i / F][i % F] = (vv < N_NODES) ? h[(size_t)vv * F + (i % F)] : 0.f;
        }
        __syncthreads();
        const int base = grp * 16;
        const int nmax = (N_NODES - v0 - base >= 16) ? 16
                        : (N_NODES - v0 - base > 0 ? N_NODES - v0 - base : 0);
#pragma unroll 2
        for (int n = 0; n < nmax; ++n) {
            const int v = v0 + base + n;
            const float4* hr4 = (const float4*)hs[base + n];
            float a0 = bias, a1 = 0.f, a2 = 0.f, a3 = 0.f;
#pragma unroll
            for (int k4 = 0; k4 < F / 4; ++k4) {
                float4 hv = hr4[k4];
                a0 += hv.x * w[4 * k4 + 0];
                a1 += hv.y * w[4 * k4 + 1];
                a2 += hv.z * w[4 * k4 + 2];
                a3 += hv.w * w[4 * k4 + 3];
            }
            float acc = (a0 + a1) + (a2 + a3);
            if (is_src) Ps[(size_t)v * H + cc] = f2b(acc);
            else        Pd[(size_t)v * H + cc] = acc;
        }
    }
}

// ---------------- fused conv: CSR gather + mean; writes m into Pd in place --
template <int H>
__global__ __launch_bounds__(256) void conv_k(
        const int* __restrict__ row_ptr, const int* __restrict__ srcs,
        const _Float16* __restrict__ e16s,
        float* __restrict__ Pd, const u16* __restrict__ Ps,
        const float* __restrict__ Wae) {
    constexpr int SL = (H >= 64) ? 64 : 32;   // lanes per node
    constexpr int NPW = 64 / SL;              // nodes per wave
    constexpr int CPL = H / SL;               // channels per lane
    constexpr int NPB = 4 * NPW;              // nodes per block per iter
    const int wave = threadIdx.x >> 6, lane = threadIdx.x & 63;
    const int sub = lane / SL;
    const int sl = lane % SL;
    const int c0 = sl * CPL;
    h2 w2h[8][CPL];
#pragma unroll
    for (int k2 = 0; k2 < 8; ++k2)
#pragma unroll
        for (int j = 0; j < CPL; ++j) {
            h2 t;
            t.x = (_Float16)Wae[(2 * k2) * H + c0 + j];
            t.y = (_Float16)Wae[(2 * k2 + 1) * H + c0 + j];
            w2h[k2][j] = t;
        }

    for (int v = blockIdx.x * NPB + wave * NPW + sub; v < N_NODES; v += gridDim.x * NPB) {
        // SL==64: v is wave-uniform; readfirstlane makes that provable so
        // row_ptr / srcs / e16 loads get scalar (SGPR) addressing.
        const int vv = (SL == 64) ? __builtin_amdgcn_readfirstlane(v) : v;
        float pd[CPL], acc[CPL];
        ld_f32<CPL>(&Pd[(size_t)vv * H + c0], pd);
#pragma unroll
        for (int j = 0; j < CPL; ++j) acc[j] = 0.f;
        const int p0 = row_ptr[vv], p1 = row_ptr[vv + 1];
        const int deg = p1 - p0;

        auto edge = [&](uint4 ra, uint4 rb, const float ps[CPL]) {
            union { u32 u; h2 h; } cv;
            h2 ev[8];
            cv.u = ra.x; ev[0] = cv.h; cv.u = ra.y; ev[1] = cv.h;
            cv.u = ra.z; ev[2] = cv.h; cv.u = ra.w; ev[3] = cv.h;
            cv.u = rb.x; ev[4] = cv.h; cv.u = rb.y; ev[5] = cv.h;
            cv.u = rb.z; ev[6] = cv.h; cv.u = rb.w; ev[7] = cv.h;
            float z[CPL];
#pragma unroll
            for (int j = 0; j < CPL; ++j) z[j] = pd[j] + ps[j];
#pragma unroll
            for (int k2 = 0; k2 < 8; ++k2)
#pragma unroll
                for (int j = 0; j < CPL; ++j) z[j] = DOT2(ev[k2], w2h[k2][j], z[j]);
#pragma unroll
            for (int j = 0; j < CPL; ++j) acc[j] += fmaxf(z[j], 0.f);
        };

        int p = p0;
        // 4-edge unroll: 4 independent srcs->Ps chains + 8 uint4 e16 loads in
        // flight per iteration.
        for (; p + 3 < p1; p += 4) {
            int s0 = srcs[p], s1 = srcs[p + 1], s2 = srcs[p + 2], s3 = srcs[p + 3];
            const uint4* e0 = (const uint4*)(e16s + (size_t)p * 16);
            uint4 a0 = e0[0], a1 = e0[1];
            uint4 b0 = e0[2], b1 = e0[3];
            uint4 g0 = e0[4], g1 = e0[5];
            uint4 d0 = e0[6], d1 = e0[7];
            float ps0[CPL], ps1[CPL], ps2[CPL], ps3[CPL];
            ld_bf16<CPL>(&Ps[(size_t)s0 * H + c0], ps0);
            ld_bf16<CPL>(&Ps[(size_t)s1 * H + c0], ps1);
            ld_bf16<CPL>(&Ps[(size_t)s2 * H + c0], ps2);
            ld_bf16<CPL>(&Ps[(size_t)s3 * H + c0], ps3);
            edge(a0, a1, ps0);
            edge(b0, b1, ps1);
            edge(g0, g1, ps2);
            edge(d0, d1, ps3);
        }
        for (; p < p1; ++p) {
            int s0 = srcs[p];
            const uint4* e0 = (const uint4*)(e16s + (size_t)p * 16);
            uint4 a0 = e0[0], a1 = e0[1];
            float ps0[CPL];
            ld_bf16<CPL>(&Ps[(size_t)s0 * H + c0], ps0);
            edge(a0, a1, ps0);
        }

        // mean; write m back into Pd[v] (only this wave ever touches Pd[v])
        const float invd = (deg > 0) ? 1.f / (float)deg : 0.f;
        if constexpr (CPL == 2) {
            float2 o; o.x = acc[0] * invd; o.y = acc[1] * invd;
            *(float2*)&Pd[(size_t)vv * H + c0] = o;
        } else {
            Pd[(size_t)vv * H + c0] = acc[0] * invd;
        }
    }
}

// ---------------- y = m @ Wb + bb (deg>0 mask) + fused BN stats ----------
// Lane owns one output channel c; Wb column cached in VGPRs (full unroll);
// grid-stride over nodes; stats accumulate in registers, flushed once.
template <int H, int Fo>
__global__ __launch_bounds__(256) void matvec_k(const float* __restrict__ m,
        const int* __restrict__ row_ptr,
        const float* __restrict__ Wb, const float* __restrict__ bb,
        float* __restrict__ y, float* __restrict__ stats) {
    constexpr int NPW = 64 / Fo;              // nodes per wave: 1/2/4
    constexpr int NPB = 4 * NPW;              // nodes per block per iter
    __shared__ float sh[2 * Fo];
    if (threadIdx.x < 2 * Fo) sh[threadIdx.x] = 0.f;
    const int wave = threadIdx.x >> 6, lane = threadIdx.x & 63;
    const int sub = lane / Fo;
    const int c = lane % Fo;
    float w[H];
#pragma unroll
    for (int k = 0; k < H; ++k) w[k] = Wb[(size_t)k * Fo + c];
    const float bias = bb[c];
    float s1 = 0.f, s2 = 0.f;

    for (int v = blockIdx.x * NPB + wave * NPW + sub; v < N_NODES; v += gridDim.x * NPB) {
        const int deg = row_ptr[v + 1] - row_ptr[v];
        const float4* mr4 = (const float4*)(m + (size_t)v * H);
        float a0 = bias, a1 = 0.f, a2 = 0.f, a3 = 0.f;
#pragma unroll
        for (int k4 = 0; k4 < H / 4; ++k4) {
            float4 mv = mr4[k4];
            a0 += mv.x * w[4 * k4 + 0];
            a1 += mv.y * w[4 * k4 + 1];
            a2 += mv.z * w[4 * k4 + 2];
            a3 += mv.w * w[4 * k4 + 3];
        }
        float val = (deg > 0) ? (a0 + a1) + (a2 + a3) : 0.f;
        y[(size_t)v * Fo + c] = val;
        s1 += val; s2 += val * val;
    }
    __syncthreads();
    atomicAdd(&sh[c], s1);
    atomicAdd(&sh[Fo + c], s2);
    __syncthreads();
    if (threadIdx.x < 2 * Fo) atomicAdd(&stats[threadIdx.x], sh[threadIdx.x]);
}

// ---------------- BN normalize ----------------
template <int Fo>
__global__ __launch_bounds__(256) void bnrelu_k(float* __restrict__ y,
        const float* __restrict__ stats, const float* __restrict__ g, const float* __restrict__ beta) {
    int idx = blockIdx.x * 256 + threadIdx.x;
    if (idx >= N_NODES * Fo) return;
    int co = idx % Fo;
    const float invN = 1.0f / (float)N_NODES;
    float mu = stats[co] * invN;
    float ex2 = stats[Fo + co] * invN;
    float var = fmaxf(ex2 - mu * mu, 0.f);
    float rs = rsqrtf(var + 1e-5f);
    y[idx] = fmaxf((y[idx] - mu) * rs * g[co] + beta[co], 0.f);
}

// ---------------- pooling & head ----------------
__global__ __launch_bounds__(256) void pool_k(const float* __restrict__ h,
        const int* __restrict__ batch, float* __restrict__ pool, int* __restrict__ gcnt) {
    int idx = blockIdx.x * 256 + threadIdx.x;
    if (idx >= N_NODES * 16) return;
    int v = idx >> 4, c = idx & 15;
    int b = batch[v];
    atomicAdd(&pool[b * 16 + c], h[idx]);
    if (c == 0) atomicAdd(&gcnt[b], 1);
}

__global__ __launch_bounds__(256) void out_k(const float* __restrict__ pool,
        const int* __restrict__ gcnt, const float* __restrict__ Wfc,
        const float* __restrict__ bfc, float* __restrict__ out) {
    int idx = blockIdx.x * 256 + threadIdx.x;
    if (idx >= NUM_GRAPHS * 12) return;
    int g = idx / 12, o = idx % 12;
    int cnt = gcnt[g];
    float inv = 1.0f / (float)(cnt > 0 ? cnt : 1);
    float acc = bfc[o];
#pragma unroll
    for (int k = 0; k < 16; ++k) acc += pool[g * 16 + k] * inv * Wfc[k * 12 + o];
    out[idx] = 1.0f / (1.0f + expf(-acc));
}

extern "C" void kernel_launch(void* const* d_in, const int* in_sizes, int n_in,
                              void* d_out, int out_size, void* d_ws, size_t ws_size,
                              hipStream_t stream) {
    const size_t N = N_NODES, E = N_EDGES, G = NUM_GRAPHS;
    const float* x = (const float*)d_in[0];
    const float* ea = (const float*)d_in[1];
    const int* ei = (const int*)d_in[2];
    const int* srcv = ei;
    const int* dstv = ei + E;
    const int* batch = (const int*)d_in[3];
    const float* Wn = (const float*)d_in[5];  const float* bn_ = (const float*)d_in[6];
    const float* We = (const float*)d_in[7];  const float* be_ = (const float*)d_in[8];
    const float* W1a = (const float*)d_in[9]; const float* b1a = (const float*)d_in[10];
    const float* W1b = (const float*)d_in[11]; const float* b1b = (const float*)d_in[12];
    const float* W2a = (const float*)d_in[13]; const float* b2a = (const float*)d_in[14];
    const float* W2b = (const float*)d_in[15]; const float* b2b = (const float*)d_in[16];
    const float* W3a = (const float*)d_in[17]; const float* b3a = (const float*)d_in[18];
    const float* W3b = (const float*)d_in[19]; const float* b3b = (const float*)d_in[20];
    const float* g1 = (const float*)d_in[21]; const float* be1 = (const float*)d_in[22];
    const float* g2 = (const float*)d_in[23]; const float* be2 = (const float*)d_in[24];
    const float* g3 = (const float*)d_in[25]; const float* be3 = (const float*)d_in[26];
    const float* Wfc = (const float*)d_in[27]; const float* bfc = (const float*)d_in[28];

    char* base = (char*)d_ws;
    size_t off = 0;
    auto take = [&](size_t bytes) { size_t o = off; off += (bytes + 255) & ~(size_t)255; return o; };
    int* hist = (int*)(base + take(N * 4));
    int* cursor = (int*)(base + take(N * 4));
    int* row_ptr = (int*)(base + take((N + 1) * 4));
    int* bsum = (int*)(base + take(256 * 4));
    int* boff = (int*)(base + take(256 * 4));
    int* sorted = (int*)(base + take(E * 4));
    int* srcs = (int*)(base + take(E * 4));
    float* hbuf = (float*)(base + take(N * 64 * 4));
    float* Pd = (float*)(base + take(N * 128 * 4));
    u16* Ps = (u16*)(base + take(N * 128 * 2));
    _Float16* e16s = (_Float16*)(base + take(E * 16 * 2));
    float* stats = (float*)(base + take(256 * 4));
    float* pool = (float*)(base + take(G * 16 * 4));
    int* gcnt = (int*)(base + take(G * 4));
    if (off > ws_size) {
        fprintf(stderr, "kernel_launch: ws too small: need %zu have %zu\n", off, ws_size);
        return;
    }

    const int NB = (N_NODES + 1023) / 1024;

    // CSR build (+ srcs in sorted order)
    hipMemsetAsync(hist, 0, N * 4, stream);
    hist_k<<<dim3((E + 255) / 256), dim3(256), 0, stream>>>(dstv, hist);
    scan_part_k<<<dim3(NB), dim3(256), 0, stream>>>(hist, cursor, bsum);
    scan_top_k<<<dim3(1), dim3(256), 0, stream>>>(bsum, boff, NB, &row_ptr[N_NODES]);
    scan_add_k<<<dim3((N + 255) / 256), dim3(256), 0, stream>>>(cursor, boff, row_ptr, cursor);
    scatter_k<<<dim3((E + 255) / 256), dim3(256), 0, stream>>>(srcv, dstv, cursor, sorted, srcs);

    // embeddings (e16 f16, CSR order)
    edge_emb_k<<<dim3((E * 16 + 255) / 256), dim3(256), 0, stream>>>(ea, We, be_, sorted, e16s);
    node_emb_k<<<dim3((N * 64 + 255) / 256), dim3(256), 0, stream>>>(x, Wn, bn_, hbuf);

    // conv1: F=64, H=128, Fo=64
    proj_k<64, 128><<<dim3(6250), dim3(256), 0, stream>>>(hbuf, W1a, b1a, Pd, Ps);
    conv_k<128><<<dim3(3072), dim3(256), 0, stream>>>(row_ptr, srcs, e16s, Pd, Ps, W1a + 128 * 128);
    hipMemsetAsync(stats, 0, 256 * 4, stream);
    matvec_k<128, 64><<<dim3(1024), dim3(256), 0, stream>>>(Pd, row_ptr, W1b, b1b, hbuf, stats);
    bnrelu_k<64><<<dim3((N * 64 + 255) / 256), dim3(256), 0, stream>>>(hbuf, stats, g1, be1);

    // conv2: F=64, H=64, Fo=32
    proj_k<64, 64><<<dim3(3125), dim3(256), 0, stream>>>(hbuf, W2a, b2a, Pd, Ps);
    conv_k<64><<<dim3(3072), dim3(256), 0, stream>>>(row_ptr, srcs, e16s, Pd, Ps, W2a + 128 * 64);
    hipMemsetAsync(stats, 0, 256 * 4, stream);
    matvec_k<64, 32><<<dim3(1024), dim3(256), 0, stream>>>(Pd, row_ptr, W2b, b2b, hbuf, stats);
    bnrelu_k<32><<<dim3((N * 32 + 255) / 256), dim3(256), 0, stream>>>(hbuf, stats, g2, be2);

    // conv3: F=32, H=32, Fo=16 (2 nodes/wave)
    proj_k<32, 32><<<dim3(1563), dim3(256), 0, stream>>>(hbuf, W3a, b3a, Pd, Ps);
    conv_k<32><<<dim3(3072), dim3(256), 0, stream>>>(row_ptr, srcs, e16s, Pd, Ps, W3a + 64 * 32);
    hipMemsetAsync(stats, 0, 256 * 4, stream);
    matvec_k<32, 16><<<dim3(1024), dim3(256), 0, stream>>>(Pd, row_ptr, W3b, b3b, hbuf, stats);
    bnrelu_k<16><<<dim3((N * 16 + 255) / 256), dim3(256), 0, stream>>>(hbuf, stats, g3, be3);

    // pool + head
    hipMemsetAsync(pool, 0, G * 16 * 4, stream);
    hipMemsetAsync(gcnt, 0, G * 4, stream);
    pool_k<<<dim3((N * 16 + 255) / 256), dim3(256), 0, stream>>>(hbuf, batch, pool, gcnt);
    out_k<<<dim3((G * 12 + 255) / 256), dim3(256), 0, stream>>>(pool, gcnt, Wfc, bfc, (float*)d_out);
}

// Round 4
// 1022.583 us; speedup vs baseline: 1.7402x; 1.0803x over previous
//
#include <hip/hip_runtime.h>
#include <hip/hip_bf16.h>
#include <cstdio>

// GCNTox21 — round 15. r14 post-mortem: matvec_k w[128] column did NOT fit
// registers (VGPR=88 < 128 -> compiler demoted/reloaded Wb in-loop), occ 21%,
// VALUBusy 22% -> latency-bound on broadcast global m-row loads.
// Fix: matvec2_k = 2-way k-split register-cached GEMV:
//   - lane = c_lo + 32*kh; owns channel c and k-half kh; caches w[H/2]
//     (64/32/16 regs -> always fits),
//   - node tile (TILE*H = 4096 floats = 16KB) staged in LDS coalesced;
//     hot loop = broadcast ds_read_b128 + 4 indep FMA chains, zero global,
//   - halves combined with one __shfl_xor(32) + add,
//   - degrees staged in LDS; BN stats fused in registers as in r14.
// Everything else identical to r14.

#define N_NODES 100000
#define N_EDGES 1600000
#define NUM_GRAPHS 4096

typedef unsigned short u16;
typedef unsigned int u32;
typedef _Float16 h2 __attribute__((ext_vector_type(2)));

#if defined(__has_builtin)
#if __has_builtin(__builtin_amdgcn_fdot2)
#define DOT2(a, b, c) __builtin_amdgcn_fdot2((a), (b), (c), false)
#endif
#endif
#ifndef DOT2
#define DOT2(a, b, c) ((c) + (float)(a).x * (float)(b).x + (float)(a).y * (float)(b).y)
#endif

__device__ __forceinline__ float b2f(u16 u) { union { u32 i; float f; } c; c.i = ((u32)u) << 16; return c.f; }
__device__ __forceinline__ float b2f_lo(u32 u) { union { u32 i; float f; } c; c.i = u << 16; return c.f; }
__device__ __forceinline__ float b2f_hi(u32 u) { union { u32 i; float f; } c; c.i = u & 0xffff0000u; return c.f; }
__device__ __forceinline__ u16 f2b(float f) {
    __hip_bfloat16 h = __float2bfloat16(f);
    return *reinterpret_cast<u16*>(&h);
}

template <int CPL>
__device__ __forceinline__ void ld_bf16(const u16* base, float out[CPL]) {
    if constexpr (CPL == 1) {
        out[0] = b2f(*base);
    } else {
        u32 v = *(const u32*)base;
        out[0] = b2f_lo(v); out[1] = b2f_hi(v);
    }
}
template <int CPL>
__device__ __forceinline__ void ld_f32(const float* base, float out[CPL]) {
    if constexpr (CPL == 1) {
        out[0] = *base;
    } else {
        float2 v = *(const float2*)base;
        out[0] = v.x; out[1] = v.y;
    }
}

// ---------------- CSR build ----------------
__global__ __launch_bounds__(256) void hist_k(const int* __restrict__ dst, int* __restrict__ hist) {
    int e = blockIdx.x * 256 + threadIdx.x;
    if (e < N_EDGES) atomicAdd(&hist[dst[e]], 1);
}

__global__ __launch_bounds__(256) void scan_part_k(const int* __restrict__ hist,
        int* __restrict__ excl, int* __restrict__ bsum) {
    __shared__ int sm[256];
    int t = threadIdx.x, b = blockIdx.x;
    int base = b * 1024 + t * 4;
    int v0 = (base + 0 < N_NODES) ? hist[base + 0] : 0;
    int v1 = (base + 1 < N_NODES) ? hist[base + 1] : 0;
    int v2 = (base + 2 < N_NODES) ? hist[base + 2] : 0;
    int v3 = (base + 3 < N_NODES) ? hist[base + 3] : 0;
    int tsum = v0 + v1 + v2 + v3;
    sm[t] = tsum;
    __syncthreads();
    for (int o = 1; o < 256; o <<= 1) {
        int x = (t >= o) ? sm[t - o] : 0;
        __syncthreads();
        sm[t] += x;
        __syncthreads();
    }
    int texcl = sm[t] - tsum;
    if (base + 0 < N_NODES) excl[base + 0] = texcl;
    if (base + 1 < N_NODES) excl[base + 1] = texcl + v0;
    if (base + 2 < N_NODES) excl[base + 2] = texcl + v0 + v1;
    if (base + 3 < N_NODES) excl[base + 3] = texcl + v0 + v1 + v2;
    if (t == 255) bsum[b] = sm[255];
}

__global__ __launch_bounds__(256) void scan_top_k(int* __restrict__ bsum, int* __restrict__ boff,
        int nb, int* __restrict__ row_ptr_last) {
    __shared__ int sm[256];
    int t = threadIdx.x;
    int v = (t < nb) ? bsum[t] : 0;
    sm[t] = v;
    __syncthreads();
    for (int o = 1; o < 256; o <<= 1) {
        int x = (t >= o) ? sm[t - o] : 0;
        __syncthreads();
        sm[t] += x;
        __syncthreads();
    }
    if (t < nb) boff[t] = sm[t] - v;
    if (t == 0) *row_ptr_last = sm[255];
}

__global__ __launch_bounds__(256) void scan_add_k(int* __restrict__ excl, const int* __restrict__ boff,
        int* __restrict__ row_ptr, int* __restrict__ cursor) {
    int i = blockIdx.x * 256 + threadIdx.x;
    if (i >= N_NODES) return;
    int s = excl[i] + boff[i >> 10];
    row_ptr[i] = s;
    cursor[i] = s;
}

__global__ __launch_bounds__(256) void scatter_k(const int* __restrict__ src, const int* __restrict__ dst,
        int* __restrict__ cursor, int* __restrict__ sorted_eid, int* __restrict__ srcs) {
    int e = blockIdx.x * 256 + threadIdx.x;
    if (e < N_EDGES) {
        int p = atomicAdd(&cursor[dst[e]], 1);
        sorted_eid[p] = e;
        srcs[p] = src[e];
    }
}

// ---------------- embeddings ----------------
__global__ __launch_bounds__(256) void edge_emb_k(const float* __restrict__ ea,
        const float* __restrict__ We, const float* __restrict__ be,
        const int* __restrict__ sorted_eid, _Float16* __restrict__ e16s) {
    int idx = blockIdx.x * 256 + threadIdx.x;
    if (idx >= N_EDGES * 16) return;
    int p = idx >> 4, k = idx & 15;
    int e = sorted_eid[p];
    float acc = be[k];
#pragma unroll
    for (int j = 0; j < 8; ++j) acc += ea[(size_t)e * 8 + j] * We[j * 16 + k];
    e16s[idx] = (_Float16)fmaxf(acc, 0.f);
}

__global__ __launch_bounds__(256) void node_emb_k(const float* __restrict__ x,
        const float* __restrict__ Wn, const float* __restrict__ bn_, float* __restrict__ h) {
    int idx = blockIdx.x * 256 + threadIdx.x;
    if (idx >= N_NODES * 64) return;
    int v = idx >> 6, c = idx & 63;
    float acc = bn_[c];
    for (int k = 0; k < 32; ++k) acc += x[(size_t)v * 32 + k] * Wn[(size_t)k * 64 + c];
    h[idx] = fmaxf(acc, 0.f);
}

// ---------------- projections: Pd fp32, Ps bf16 ----------------
// Register-weight-cached broadcast GEMM. Thread owns one of 2H fused output
// channels; Wa column lives in VGPRs; node tiles staged in LDS.
template <int F, int H>
__global__ __launch_bounds__(256) void proj_k(const float* __restrict__ h,
        const float* __restrict__ Wa, const float* __restrict__ ba,
        float* __restrict__ Pd, u16* __restrict__ Ps) {
    constexpr int C2 = 2 * H;            // fused output channels per node
    constexpr int NPB = 256 / C2;        // node subgroups per block: 1/2/4
    constexpr int TILE = 16 * NPB;       // nodes staged per tile
    __shared__ float hs[TILE][F];        // 4KB / 8KB / 8KB
    const int t = threadIdx.x;
    const int grp = t / C2;
    const int c = t % C2;
    const bool is_src = (c >= H);
    const int cc = is_src ? (c - H) : c;
    // register-cache weight column Wa[(is_src?F:0)+k][cc]
    float w[F];
    const float* wcol = Wa + (size_t)(is_src ? F : 0) * H + cc;
#pragma unroll
    for (int k = 0; k < F; ++k) w[k] = wcol[(size_t)k * H];
    const float bias = is_src ? 0.f : ba[cc];

    for (int v0 = blockIdx.x * TILE; v0 < N_NODES; v0 += gridDim.x * TILE) {
        __syncthreads();
        for (int i = t; i < TILE * F; i += 256) {
            int vv = v0 + i / F;
            hs[i / F][i % F] = (vv < N_NODES) ? h[(size_t)vv * F + (i % F)] : 0.f;
        }
        __syncthreads();
        const int base = grp * 16;
        const int nmax = (N_NODES - v0 - base >= 16) ? 16
                        : (N_NODES - v0 - base > 0 ? N_NODES - v0 - base : 0);
#pragma unroll 2
        for (int n = 0; n < nmax; ++n) {
            const int v = v0 + base + n;
            const float4* hr4 = (const float4*)hs[base + n];
            float a0 = bias, a1 = 0.f, a2 = 0.f, a3 = 0.f;
#pragma unroll
            for (int k4 = 0; k4 < F / 4; ++k4) {
                float4 hv = hr4[k4];
                a0 += hv.x * w[4 * k4 + 0];
                a1 += hv.y * w[4 * k4 + 1];
                a2 += hv.z * w[4 * k4 + 2];
                a3 += hv.w * w[4 * k4 + 3];
            }
            float acc = (a0 + a1) + (a2 + a3);
            if (is_src) Ps[(size_t)v * H + cc] = f2b(acc);
            else        Pd[(size_t)v * H + cc] = acc;
        }
    }
}

// ---------------- fused conv: CSR gather + mean; writes m into Pd in place --
template <int H>
__global__ __launch_bounds__(256) void conv_k(
        const int* __restrict__ row_ptr, const int* __restrict__ srcs,
        const _Float16* __restrict__ e16s,
        float* __restrict__ Pd, const u16* __restrict__ Ps,
        const float* __restrict__ Wae) {
    constexpr int SL = (H >= 64) ? 64 : 32;   // lanes per node
    constexpr int NPW = 64 / SL;              // nodes per wave
    constexpr int CPL = H / SL;               // channels per lane
    constexpr int NPB = 4 * NPW;              // nodes per block per iter
    const int wave = threadIdx.x >> 6, lane = threadIdx.x & 63;
    const int sub = lane / SL;
    const int sl = lane % SL;
    const int c0 = sl * CPL;
    h2 w2h[8][CPL];
#pragma unroll
    for (int k2 = 0; k2 < 8; ++k2)
#pragma unroll
        for (int j = 0; j < CPL; ++j) {
            h2 t;
            t.x = (_Float16)Wae[(2 * k2) * H + c0 + j];
            t.y = (_Float16)Wae[(2 * k2 + 1) * H + c0 + j];
            w2h[k2][j] = t;
        }

    for (int v = blockIdx.x * NPB + wave * NPW + sub; v < N_NODES; v += gridDim.x * NPB) {
        // SL==64: v is wave-uniform; readfirstlane makes that provable so
        // row_ptr / srcs / e16 loads get scalar (SGPR) addressing.
        const int vv = (SL == 64) ? __builtin_amdgcn_readfirstlane(v) : v;
        float pd[CPL], acc[CPL];
        ld_f32<CPL>(&Pd[(size_t)vv * H + c0], pd);
#pragma unroll
        for (int j = 0; j < CPL; ++j) acc[j] = 0.f;
        const int p0 = row_ptr[vv], p1 = row_ptr[vv + 1];
        const int deg = p1 - p0;

        auto edge = [&](uint4 ra, uint4 rb, const float ps[CPL]) {
            union { u32 u; h2 h; } cv;
            h2 ev[8];
            cv.u = ra.x; ev[0] = cv.h; cv.u = ra.y; ev[1] = cv.h;
            cv.u = ra.z; ev[2] = cv.h; cv.u = ra.w; ev[3] = cv.h;
            cv.u = rb.x; ev[4] = cv.h; cv.u = rb.y; ev[5] = cv.h;
            cv.u = rb.z; ev[6] = cv.h; cv.u = rb.w; ev[7] = cv.h;
            float z[CPL];
#pragma unroll
            for (int j = 0; j < CPL; ++j) z[j] = pd[j] + ps[j];
#pragma unroll
            for (int k2 = 0; k2 < 8; ++k2)
#pragma unroll
                for (int j = 0; j < CPL; ++j) z[j] = DOT2(ev[k2], w2h[k2][j], z[j]);
#pragma unroll
            for (int j = 0; j < CPL; ++j) acc[j] += fmaxf(z[j], 0.f);
        };

        int p = p0;
        // 4-edge unroll: 4 independent srcs->Ps chains + 8 uint4 e16 loads in
        // flight per iteration.
        for (; p + 3 < p1; p += 4) {
            int s0 = srcs[p], s1 = srcs[p + 1], s2 = srcs[p + 2], s3 = srcs[p + 3];
            const uint4* e0 = (const uint4*)(e16s + (size_t)p * 16);
            uint4 a0 = e0[0], a1 = e0[1];
            uint4 b0 = e0[2], b1 = e0[3];
            uint4 g0 = e0[4], g1 = e0[5];
            uint4 d0 = e0[6], d1 = e0[7];
            float ps0[CPL], ps1[CPL], ps2[CPL], ps3[CPL];
            ld_bf16<CPL>(&Ps[(size_t)s0 * H + c0], ps0);
            ld_bf16<CPL>(&Ps[(size_t)s1 * H + c0], ps1);
            ld_bf16<CPL>(&Ps[(size_t)s2 * H + c0], ps2);
            ld_bf16<CPL>(&Ps[(size_t)s3 * H + c0], ps3);
            edge(a0, a1, ps0);
            edge(b0, b1, ps1);
            edge(g0, g1, ps2);
            edge(d0, d1, ps3);
        }
        for (; p < p1; ++p) {
            int s0 = srcs[p];
            const uint4* e0 = (const uint4*)(e16s + (size_t)p * 16);
            uint4 a0 = e0[0], a1 = e0[1];
            float ps0[CPL];
            ld_bf16<CPL>(&Ps[(size_t)s0 * H + c0], ps0);
            edge(a0, a1, ps0);
        }

        // mean; write m back into Pd[v] (only this wave ever touches Pd[v])
        const float invd = (deg > 0) ? 1.f / (float)deg : 0.f;
        if constexpr (CPL == 2) {
            float2 o; o.x = acc[0] * invd; o.y = acc[1] * invd;
            *(float2*)&Pd[(size_t)vv * H + c0] = o;
        } else {
            Pd[(size_t)vv * H + c0] = acc[0] * invd;
        }
    }
}

// ---------------- y = m @ Wb + bb (deg>0 mask) + fused BN stats ----------
// 2-way k-split register-cached GEMV over LDS-staged node tiles.
// lane = c_lo + 32*kh: channel c_lo (within wave's channel group), k-half kh.
// w[H/2] in VGPRs; hot loop = broadcast ds_read_b128 + 4 indep FMA chains;
// halves combined via __shfl_xor(32).
template <int H, int Fo>
__global__ __launch_bounds__(256) void matvec2_k(const float* __restrict__ m,
        const int* __restrict__ row_ptr,
        const float* __restrict__ Wb, const float* __restrict__ bb,
        float* __restrict__ y, float* __restrict__ stats) {
    constexpr int FoC = (Fo < 32) ? Fo : 32;  // channels per wave: 32/32/16
    constexpr int CG = Fo / FoC;              // channel groups: 2/1/1
    constexpr int NPW = 32 / FoC;             // node subs per half-wave: 1/1/2
    constexpr int NG = 4 / CG;                // node groups (waves): 2/4/4
    constexpr int SLOTS = NG * NPW;           // node slots per pass: 2/4/8
    constexpr int KH = H / 2;                 // k per lane: 64/32/16
    constexpr int TILE = 4096 / H;            // nodes per tile: 32/64/128
    constexpr int J = TILE / SLOTS;           // 16 for all shapes

    __shared__ float hs[TILE * H];            // 16 KB
    __shared__ int ptile[TILE + 1];
    __shared__ float sh[2 * Fo];

    const int t = threadIdx.x;
    const int wave = t >> 6, lane = t & 63;
    const int kh = lane >> 5;
    const int r = lane & 31;
    const int c_lo = r % FoC;
    const int s = r / FoC;
    const int cg = wave % CG;
    const int ng = wave / CG;
    const int c = cg * FoC + c_lo;
    const int slot = ng * NPW + s;

    for (int i = t; i < 2 * Fo; i += 256) sh[i] = 0.f;

    // register-cache this lane's k-half of Wb column c
    float w[KH];
#pragma unroll
    for (int k = 0; k < KH; ++k) w[k] = Wb[(size_t)(kh * KH + k) * Fo + c];
    const float bias = bb[c];
    float s1 = 0.f, s2 = 0.f;

    const float4* msrc = (const float4*)m;
    float4* hs4 = (float4*)hs;

    for (int v0 = blockIdx.x * TILE; v0 < N_NODES; v0 += gridDim.x * TILE) {
        __syncthreads();
        // stage tile: 1024 float4s, 4 per thread, coalesced
#pragma unroll
        for (int q = t; q < 1024; q += 256) {
            int node = (q * 4) / H;
            float4 val;
            if (v0 + node < N_NODES) val = msrc[(size_t)v0 * (H / 4) + q];
            else { val.x = val.y = val.z = val.w = 0.f; }
            hs4[q] = val;
        }
        for (int i = t; i <= TILE; i += 256) {
            int v = v0 + i;
            ptile[i] = row_ptr[v < N_NODES ? v : N_NODES];
        }
        __syncthreads();

        for (int j = 0; j < J; ++j) {
            const int n = slot + j * SLOTS;
            const int v = v0 + n;
            const float4* hr4 = (const float4*)&hs[n * H + kh * KH];
            float a0 = 0.f, a1 = 0.f, a2 = 0.f, a3 = 0.f;
#pragma unroll
            for (int k4 = 0; k4 < KH / 4; ++k4) {
                float4 hv = hr4[k4];
                a0 += hv.x * w[4 * k4 + 0];
                a1 += hv.y * w[4 * k4 + 1];
                a2 += hv.z * w[4 * k4 + 2];
                a3 += hv.w * w[4 * k4 + 3];
            }
            float half = (a0 + a1) + (a2 + a3);
            float total = half + __shfl_xor(half, 32) + bias;
            if (kh == 0 && v < N_NODES) {
                const int deg = ptile[n + 1] - ptile[n];
                float val = (deg > 0) ? total : 0.f;
                y[(size_t)v * Fo + c] = val;
                s1 += val; s2 += val * val;
            }
        }
    }

    __syncthreads();
    if (kh == 0) {
        atomicAdd(&sh[c], s1);
        atomicAdd(&sh[Fo + c], s2);
    }
    __syncthreads();
    if (t < 2 * Fo) atomicAdd(&stats[t], sh[t]);
}

// ---------------- BN normalize ----------------
template <int Fo>
__global__ __launch_bounds__(256) void bnrelu_k(float* __restrict__ y,
        const float* __restrict__ stats, const float* __restrict__ g, const float* __restrict__ beta) {
    int idx = blockIdx.x * 256 + threadIdx.x;
    if (idx >= N_NODES * Fo) return;
    int co = idx % Fo;
    const float invN = 1.0f / (float)N_NODES;
    float mu = stats[co] * invN;
    float ex2 = stats[Fo + co] * invN;
    float var = fmaxf(ex2 - mu * mu, 0.f);
    float rs = rsqrtf(var + 1e-5f);
    y[idx] = fmaxf((y[idx] - mu) * rs * g[co] + beta[co], 0.f);
}

// ---------------- pooling & head ----------------
__global__ __launch_bounds__(256) void pool_k(const float* __restrict__ h,
        const int* __restrict__ batch, float* __restrict__ pool, int* __restrict__ gcnt) {
    int idx = blockIdx.x * 256 + threadIdx.x;
    if (idx >= N_NODES * 16) return;
    int v = idx >> 4, c = idx & 15;
    int b = batch[v];
    atomicAdd(&pool[b * 16 + c], h[idx]);
    if (c == 0) atomicAdd(&gcnt[b], 1);
}

__global__ __launch_bounds__(256) void out_k(const float* __restrict__ pool,
        const int* __restrict__ gcnt, const float* __restrict__ Wfc,
        const float* __restrict__ bfc, float* __restrict__ out) {
    int idx = blockIdx.x * 256 + threadIdx.x;
    if (idx >= NUM_GRAPHS * 12) return;
    int g = idx / 12, o = idx % 12;
    int cnt = gcnt[g];
    float inv = 1.0f / (float)(cnt > 0 ? cnt : 1);
    float acc = bfc[o];
#pragma unroll
    for (int k = 0; k < 16; ++k) acc += pool[g * 16 + k] * inv * Wfc[k * 12 + o];
    out[idx] = 1.0f / (1.0f + expf(-acc));
}

extern "C" void kernel_launch(void* const* d_in, const int* in_sizes, int n_in,
                              void* d_out, int out_size, void* d_ws, size_t ws_size,
                              hipStream_t stream) {
    const size_t N = N_NODES, E = N_EDGES, G = NUM_GRAPHS;
    const float* x = (const float*)d_in[0];
    const float* ea = (const float*)d_in[1];
    const int* ei = (const int*)d_in[2];
    const int* srcv = ei;
    const int* dstv = ei + E;
    const int* batch = (const int*)d_in[3];
    const float* Wn = (const float*)d_in[5];  const float* bn_ = (const float*)d_in[6];
    const float* We = (const float*)d_in[7];  const float* be_ = (const float*)d_in[8];
    const float* W1a = (const float*)d_in[9]; const float* b1a = (const float*)d_in[10];
    const float* W1b = (const float*)d_in[11]; const float* b1b = (const float*)d_in[12];
    const float* W2a = (const float*)d_in[13]; const float* b2a = (const float*)d_in[14];
    const float* W2b = (const float*)d_in[15]; const float* b2b = (const float*)d_in[16];
    const float* W3a = (const float*)d_in[17]; const float* b3a = (const float*)d_in[18];
    const float* W3b = (const float*)d_in[19]; const float* b3b = (const float*)d_in[20];
    const float* g1 = (const float*)d_in[21]; const float* be1 = (const float*)d_in[22];
    const float* g2 = (const float*)d_in[23]; const float* be2 = (const float*)d_in[24];
    const float* g3 = (const float*)d_in[25]; const float* be3 = (const float*)d_in[26];
    const float* Wfc = (const float*)d_in[27]; const float* bfc = (const float*)d_in[28];

    char* base = (char*)d_ws;
    size_t off = 0;
    auto take = [&](size_t bytes) { size_t o = off; off += (bytes + 255) & ~(size_t)255; return o; };
    int* hist = (int*)(base + take(N * 4));
    int* cursor = (int*)(base + take(N * 4));
    int* row_ptr = (int*)(base + take((N + 1) * 4));
    int* bsum = (int*)(base + take(256 * 4));
    int* boff = (int*)(base + take(256 * 4));
    int* sorted = (int*)(base + take(E * 4));
    int* srcs = (int*)(base + take(E * 4));
    float* hbuf = (float*)(base + take(N * 64 * 4));
    float* Pd = (float*)(base + take(N * 128 * 4));
    u16* Ps = (u16*)(base + take(N * 128 * 2));
    _Float16* e16s = (_Float16*)(base + take(E * 16 * 2));
    float* stats = (float*)(base + take(256 * 4));
    float* pool = (float*)(base + take(G * 16 * 4));
    int* gcnt = (int*)(base + take(G * 4));
    if (off > ws_size) {
        fprintf(stderr, "kernel_launch: ws too small: need %zu have %zu\n", off, ws_size);
        return;
    }

    const int NB = (N_NODES + 1023) / 1024;

    // CSR build (+ srcs in sorted order)
    hipMemsetAsync(hist, 0, N * 4, stream);
    hist_k<<<dim3((E + 255) / 256), dim3(256), 0, stream>>>(dstv, hist);
    scan_part_k<<<dim3(NB), dim3(256), 0, stream>>>(hist, cursor, bsum);
    scan_top_k<<<dim3(1), dim3(256), 0, stream>>>(bsum, boff, NB, &row_ptr[N_NODES]);
    scan_add_k<<<dim3((N + 255) / 256), dim3(256), 0, stream>>>(cursor, boff, row_ptr, cursor);
    scatter_k<<<dim3((E + 255) / 256), dim3(256), 0, stream>>>(srcv, dstv, cursor, sorted, srcs);

    // embeddings (e16 f16, CSR order)
    edge_emb_k<<<dim3((E * 16 + 255) / 256), dim3(256), 0, stream>>>(ea, We, be_, sorted, e16s);
    node_emb_k<<<dim3((N * 64 + 255) / 256), dim3(256), 0, stream>>>(x, Wn, bn_, hbuf);

    // conv1: F=64, H=128, Fo=64
    proj_k<64, 128><<<dim3(6250), dim3(256), 0, stream>>>(hbuf, W1a, b1a, Pd, Ps);
    conv_k<128><<<dim3(3072), dim3(256), 0, stream>>>(row_ptr, srcs, e16s, Pd, Ps, W1a + 128 * 128);
    hipMemsetAsync(stats, 0, 256 * 4, stream);
    matvec2_k<128, 64><<<dim3(1024), dim3(256), 0, stream>>>(Pd, row_ptr, W1b, b1b, hbuf, stats);
    bnrelu_k<64><<<dim3((N * 64 + 255) / 256), dim3(256), 0, stream>>>(hbuf, stats, g1, be1);

    // conv2: F=64, H=64, Fo=32
    proj_k<64, 64><<<dim3(3125), dim3(256), 0, stream>>>(hbuf, W2a, b2a, Pd, Ps);
    conv_k<64><<<dim3(3072), dim3(256), 0, stream>>>(row_ptr, srcs, e16s, Pd, Ps, W2a + 128 * 64);
    hipMemsetAsync(stats, 0, 256 * 4, stream);
    matvec2_k<64, 32><<<dim3(1024), dim3(256), 0, stream>>>(Pd, row_ptr, W2b, b2b, hbuf, stats);
    bnrelu_k<32><<<dim3((N * 32 + 255) / 256), dim3(256), 0, stream>>>(hbuf, stats, g2, be2);

    // conv3: F=32, H=32, Fo=16 (2 nodes/wave)
    proj_k<32, 32><<<dim3(1563), dim3(256), 0, stream>>>(hbuf, W3a, b3a, Pd, Ps);
    conv_k<32><<<dim3(3072), dim3(256), 0, stream>>>(row_ptr, srcs, e16s, Pd, Ps, W3a + 64 * 32);
    hipMemsetAsync(stats, 0, 256 * 4, stream);
    matvec2_k<32, 16><<<dim3(1024), dim3(256), 0, stream>>>(Pd, row_ptr, W3b, b3b, hbuf, stats);
    bnrelu_k<16><<<dim3((N * 16 + 255) / 256), dim3(256), 0, stream>>>(hbuf, stats, g3, be3);

    // pool + head
    hipMemsetAsync(pool, 0, G * 16 * 4, stream);
    hipMemsetAsync(gcnt, 0, G * 4, stream);
    pool_k<<<dim3((N * 16 + 255) / 256), dim3(256), 0, stream>>>(hbuf, batch, pool, gcnt);
    out_k<<<dim3((G * 12 + 255) / 256), dim3(256), 0, stream>>>(pool, gcnt, Wfc, bfc, (float*)d_out);
}